// Round 1
// baseline (710.922 us; speedup 1.0000x reference)
//
#include <hip/hip_runtime.h>
#include <math.h>

#define D_MODEL   512
#define D_INNER   1024
#define NHEADS    64
#define HEADDIM   16
#define D_STATE   16
#define CONV_DIM  1056
#define D_IN_PROJ 2144
#define CHUNK     256
#define NCHUNK    16
#define BATCH     2
#define SEQ       4096
#define ROWS      (BATCH * SEQ)   // 8192

__device__ __forceinline__ float softplusf(float x) {
    return (x > 20.f) ? x : log1pf(expf(x));
}
__device__ __forceinline__ float siluf(float x) {
    return x / (1.f + expf(-x));
}

// C[M,N] = A[M,K] @ B[N,K]^T   (A,B row-major; weights stored as [N,K])
// 64x64 tile, 256 threads, 4x4 micro-tile per thread, K-step 16.
__global__ __launch_bounds__(256) void gemm_bt(const float* __restrict__ A,
                                               const float* __restrict__ B,
                                               float* __restrict__ C,
                                               int M, int N, int K) {
    __shared__ float As[16][64];
    __shared__ float Bs[16][64];
    const int t    = threadIdx.x;
    const int bm   = blockIdx.y * 64;
    const int bn   = blockIdx.x * 64;
    const int lrow = t >> 2;          // 0..63
    const int kq   = (t & 3) << 2;    // 0,4,8,12
    const int ty   = t >> 4;          // 0..15
    const int tx   = t & 15;          // 0..15

    float acc[4][4] = {};
    for (int k0 = 0; k0 < K; k0 += 16) {
        float4 av = *(const float4*)(A + (size_t)(bm + lrow) * K + k0 + kq);
        As[kq + 0][lrow] = av.x; As[kq + 1][lrow] = av.y;
        As[kq + 2][lrow] = av.z; As[kq + 3][lrow] = av.w;
        float4 bv = make_float4(0.f, 0.f, 0.f, 0.f);
        if (bn + lrow < N)
            bv = *(const float4*)(B + (size_t)(bn + lrow) * K + k0 + kq);
        Bs[kq + 0][lrow] = bv.x; Bs[kq + 1][lrow] = bv.y;
        Bs[kq + 2][lrow] = bv.z; Bs[kq + 3][lrow] = bv.w;
        __syncthreads();
        #pragma unroll
        for (int kk = 0; kk < 16; ++kk) {
            float a0 = As[kk][ty * 4 + 0], a1 = As[kk][ty * 4 + 1];
            float a2 = As[kk][ty * 4 + 2], a3 = As[kk][ty * 4 + 3];
            float b0 = Bs[kk][tx * 4 + 0], b1 = Bs[kk][tx * 4 + 1];
            float b2 = Bs[kk][tx * 4 + 2], b3 = Bs[kk][tx * 4 + 3];
            acc[0][0] += a0 * b0; acc[0][1] += a0 * b1; acc[0][2] += a0 * b2; acc[0][3] += a0 * b3;
            acc[1][0] += a1 * b0; acc[1][1] += a1 * b1; acc[1][2] += a1 * b2; acc[1][3] += a1 * b3;
            acc[2][0] += a2 * b0; acc[2][1] += a2 * b1; acc[2][2] += a2 * b2; acc[2][3] += a2 * b3;
            acc[3][0] += a3 * b0; acc[3][1] += a3 * b1; acc[3][2] += a3 * b2; acc[3][3] += a3 * b3;
        }
        __syncthreads();
    }
    #pragma unroll
    for (int i = 0; i < 4; ++i) {
        #pragma unroll
        for (int j = 0; j < 4; ++j) {
            int cn = bn + tx * 4 + j;
            if (cn < N)
                C[(size_t)(bm + ty * 4 + i) * N + cn] = acc[i][j];
        }
    }
}

// depthwise causal conv(4) + bias + SiLU over the xBC slice of zxbcdt
__global__ void conv_silu(const float* __restrict__ zx, const float* __restrict__ cw,
                          const float* __restrict__ cb, float* __restrict__ xc) {
    int idx = blockIdx.x * blockDim.x + threadIdx.x;
    if (idx >= ROWS * CONV_DIM) return;
    int c  = idx % CONV_DIM;
    int bl = idx / CONV_DIM;
    int l  = bl % SEQ;
    float w0 = cw[c * 4 + 0], w1 = cw[c * 4 + 1], w2 = cw[c * 4 + 2], w3 = cw[c * 4 + 3];
    const float* base = zx + (size_t)bl * D_IN_PROJ + D_INNER + c;
    float acc = cb[c];
    if (l >= 3) acc += w0 * base[-3 * D_IN_PROJ];
    if (l >= 2) acc += w1 * base[-2 * D_IN_PROJ];
    if (l >= 1) acc += w2 * base[-1 * D_IN_PROJ];
    acc += w3 * base[0];
    xc[idx] = siluf(acc);
}

__global__ void dt_softplus(const float* __restrict__ zx, const float* __restrict__ dtb,
                            float* __restrict__ dtsp) {
    int idx = blockIdx.x * blockDim.x + threadIdx.x;
    if (idx >= ROWS * NHEADS) return;
    int h  = idx & 63;
    int bl = idx >> 6;
    dtsp[idx] = softplusf(zx[(size_t)bl * D_IN_PROJ + (D_INNER + CONV_DIM) + h] + dtb[h]);
}

// per (b, chunk, head) block: intra-chunk Y_diag + end-of-chunk state
__global__ __launch_bounds__(256) void ssd_chunk(const float* __restrict__ xc,
                                                 const float* __restrict__ dtsp,
                                                 const float* __restrict__ A_log,
                                                 float* __restrict__ ypre,
                                                 float* __restrict__ states,
                                                 float* __restrict__ csb,
                                                 float* __restrict__ csum) {
    __shared__ float Bs[256][16];
    __shared__ float Cs[256][16];
    __shared__ float Xs[256][16];
    __shared__ float cs[256];
    __shared__ float dec[256];
    const int bid = blockIdx.x;
    const int h = bid & 63;
    const int c = (bid >> 6) & 15;
    const int b = bid >> 10;
    const int t = threadIdx.x;
    const int row = b * SEQ + c * CHUNK + t;

    float Ah  = -expf(A_log[h]);
    float dtv = dtsp[(size_t)row * NHEADS + h];
    float dAv = dtv * Ah;
    cs[t] = dAv;
    __syncthreads();
    for (int off = 1; off < 256; off <<= 1) {
        float v = (t >= off) ? cs[t - off] : 0.f;
        __syncthreads();
        cs[t] += v;
        __syncthreads();
    }
    const float* xrow = xc + (size_t)row * CONV_DIM;
    #pragma unroll
    for (int n = 0; n < 16; n += 4) {
        float4 bv = *(const float4*)(xrow + D_INNER + n);
        Bs[t][n] = bv.x; Bs[t][n + 1] = bv.y; Bs[t][n + 2] = bv.z; Bs[t][n + 3] = bv.w;
        float4 cv = *(const float4*)(xrow + D_INNER + D_STATE + n);
        Cs[t][n] = cv.x; Cs[t][n + 1] = cv.y; Cs[t][n + 2] = cv.z; Cs[t][n + 3] = cv.w;
        float4 xv = *(const float4*)(xrow + h * HEADDIM + n);
        Xs[t][n] = xv.x * dtv; Xs[t][n + 1] = xv.y * dtv;
        Xs[t][n + 2] = xv.z * dtv; Xs[t][n + 3] = xv.w * dtv;
    }
    float cl = cs[255];
    dec[t] = expf(cl - cs[t]);
    __syncthreads();

    // Y_diag row t
    float acc[16] = {};
    float cst = cs[t];
    float Ct[16];
    #pragma unroll
    for (int n = 0; n < 16; ++n) Ct[n] = Cs[t][n];
    for (int s = 0; s <= t; ++s) {
        float dot = 0.f;
        #pragma unroll
        for (int n = 0; n < 16; ++n) dot += Ct[n] * Bs[s][n];
        float w = dot * expf(cst - cs[s]);
        #pragma unroll
        for (int p = 0; p < 16; ++p) acc[p] += w * Xs[s][p];
    }
    float* yrow = ypre + (size_t)row * D_INNER + h * HEADDIM;
    #pragma unroll
    for (int p = 0; p < 16; ++p) yrow[p] = acc[p];

    // end-of-chunk state: thread t -> (p = t/16, n = t%16)
    const int p = t >> 4, n = t & 15;
    float st = 0.f;
    for (int s = 0; s < 256; ++s) st += dec[s] * Bs[s][n] * Xs[s][p];
    states[(size_t)bid * 256 + t] = st;
    csb[(size_t)bid * 256 + t] = cs[t];
    if (t == 255) csum[(b * 64 + h) * 16 + c] = cl;
}

// sequential inter-chunk recurrence (tiny): prev_state per chunk
__global__ __launch_bounds__(256) void ssd_rec(const float* __restrict__ states,
                                               const float* __restrict__ csum,
                                               float* __restrict__ prevst) {
    const int bh = blockIdx.x;       // b*64 + h
    const int b = bh >> 6, h = bh & 63;
    const int t = threadIdx.x;
    float run = 0.f;
    for (int c = 0; c < NCHUNK; ++c) {
        size_t idx = ((size_t)((b * 16 + c) * 64 + h)) * 256 + t;
        prevst[idx] = run;
        run = run * expf(csum[bh * 16 + c]) + states[idx];
    }
}

// Y_off + D skip + SiLU(z) gating
__global__ __launch_bounds__(256) void ssd_off(const float* __restrict__ xc,
                                               const float* __restrict__ zx,
                                               const float* __restrict__ prevst,
                                               const float* __restrict__ csb,
                                               const float* __restrict__ Dskip,
                                               float* __restrict__ ypre) {
    __shared__ float ps[256];
    const int bid = blockIdx.x;
    const int h = bid & 63;
    const int c = (bid >> 6) & 15;
    const int b = bid >> 10;
    const int t = threadIdx.x;
    ps[t] = prevst[(size_t)bid * 256 + t];
    __syncthreads();
    const int row = b * SEQ + c * CHUNK + t;
    float sdo = expf(csb[(size_t)bid * 256 + t]);
    const float* xrow = xc + (size_t)row * CONV_DIM;
    float Ct[16];
    #pragma unroll
    for (int n = 0; n < 16; ++n) Ct[n] = xrow[D_INNER + D_STATE + n];
    float d = Dskip[h];
    float* yrow = ypre + (size_t)row * D_INNER + h * HEADDIM;
    const float* zrow = zx + (size_t)row * D_IN_PROJ + h * HEADDIM;
    #pragma unroll
    for (int p = 0; p < 16; ++p) {
        float off = 0.f;
        #pragma unroll
        for (int n = 0; n < 16; ++n) off += Ct[n] * ps[p * 16 + n];
        float yv = yrow[p] + sdo * off + xrow[h * HEADDIM + p] * d;
        float z = zrow[p];
        yrow[p] = yv * siluf(z);
    }
}

__global__ __launch_bounds__(256) void rmsnorm_ip(float* __restrict__ y,
                                                  const float* __restrict__ w) {
    __shared__ float red[4];
    __shared__ float stot;
    const int row = blockIdx.x;
    const int t = threadIdx.x;
    float* yr = y + (size_t)row * D_INNER;
    float4 v = *(const float4*)(yr + t * 4);
    float ss = v.x * v.x + v.y * v.y + v.z * v.z + v.w * v.w;
    for (int off = 32; off > 0; off >>= 1) ss += __shfl_down(ss, off, 64);
    if ((t & 63) == 0) red[t >> 6] = ss;
    __syncthreads();
    if (t == 0) stot = red[0] + red[1] + red[2] + red[3];
    __syncthreads();
    float rstd = rsqrtf(stot / (float)D_INNER + 1e-5f);
    float4 wv = *(const float4*)(w + t * 4);
    v.x *= rstd * wv.x; v.y *= rstd * wv.y; v.z *= rstd * wv.z; v.w *= rstd * wv.w;
    *(float4*)(yr + t * 4) = v;
}

extern "C" void kernel_launch(void* const* d_in, const int* in_sizes, int n_in,
                              void* d_out, int out_size, void* d_ws, size_t ws_size,
                              hipStream_t stream) {
    const float* u     = (const float*)d_in[0];
    const float* Win   = (const float*)d_in[1];
    const float* cw    = (const float*)d_in[2];
    const float* cb    = (const float*)d_in[3];
    const float* dtb   = (const float*)d_in[4];
    const float* Alog  = (const float*)d_in[5];
    const float* Dsk   = (const float*)d_in[6];
    const float* normw = (const float*)d_in[7];
    const float* Wout  = (const float*)d_in[8];
    float* out = (float*)d_out;

    float* ws   = (float*)d_ws;
    float* zx   = ws;                   // 8192*2144 = 17563648
    float* xc   = zx + 17563648;        // 8192*1056 = 8650752
    float* dtsp = xc + 8650752;         // 8192*64   = 524288
    float* csb  = dtsp + 524288;        // 524288
    float* st   = csb + 524288;         // 524288
    float* pst  = st + 524288;          // 524288
    float* csum = pst + 524288;         // 2048
    float* ypre = csum + 2048;          // 8192*1024 = 8388608

    gemm_bt<<<dim3(34, 128), 256, 0, stream>>>(u, Win, zx, ROWS, D_IN_PROJ, D_MODEL);
    conv_silu<<<(ROWS * CONV_DIM + 255) / 256, 256, 0, stream>>>(zx, cw, cb, xc);
    dt_softplus<<<(ROWS * NHEADS) / 256, 256, 0, stream>>>(zx, dtb, dtsp);
    ssd_chunk<<<BATCH * NCHUNK * NHEADS, 256, 0, stream>>>(xc, dtsp, Alog, ypre, st, csb, csum);
    ssd_rec<<<BATCH * NHEADS, 256, 0, stream>>>(st, csum, pst);
    ssd_off<<<BATCH * NCHUNK * NHEADS, 256, 0, stream>>>(xc, zx, pst, csb, Dsk, ypre);
    rmsnorm_ip<<<ROWS, 256, 0, stream>>>(ypre, normw);
    gemm_bt<<<dim3(8, 128), 256, 0, stream>>>(ypre, Wout, out, ROWS, D_MODEL, D_INNER);
}

// Round 2
// 390.945 us; speedup vs baseline: 1.8185x; 1.8185x over previous
//
#include <hip/hip_runtime.h>
#include <hip/hip_bf16.h>
#include <math.h>

#define D_MODEL   512
#define D_INNER   1024
#define NHEADS    64
#define HEADDIM   16
#define D_STATE   16
#define CONV_DIM  1056
#define D_IN_PROJ 2144
#define CHUNK     256
#define NCHUNK    16
#define BATCH     2
#define SEQ       4096
#define ROWS      (BATCH * SEQ)   // 8192

typedef __bf16 bf16x8 __attribute__((ext_vector_type(8)));
typedef float  f32x4  __attribute__((ext_vector_type(4)));
typedef unsigned short u16x8 __attribute__((ext_vector_type(8)));

__device__ __forceinline__ float softplusf(float x) {
    return (x > 20.f) ? x : log1pf(expf(x));
}
__device__ __forceinline__ float siluf(float x) {
    return x / (1.f + expf(-x));
}
__device__ __forceinline__ unsigned short f2b(float x) {
    union { __hip_bfloat16 h; unsigned short u; } cv;
    cv.h = __float2bfloat16(x);
    return cv.u;
}
__device__ __forceinline__ void load_lds16(const unsigned short* g, unsigned short* l) {
    __builtin_amdgcn_global_load_lds(
        (const __attribute__((address_space(1))) void*)g,
        (__attribute__((address_space(3))) void*)l,
        16, 0, 0);
}

// ---- cast fp32 -> bf16 (8 elems/thread, 16B stores) ----
__global__ __launch_bounds__(256) void cast8(const float* __restrict__ in,
                                             unsigned short* __restrict__ out, int n) {
    int i = (blockIdx.x * blockDim.x + threadIdx.x) * 8;
    if (i >= n) return;
    float4 a = *(const float4*)(in + i);
    float4 b = *(const float4*)(in + i + 4);
    u16x8 o;
    o[0] = f2b(a.x); o[1] = f2b(a.y); o[2] = f2b(a.z); o[3] = f2b(a.w);
    o[4] = f2b(b.x); o[5] = f2b(b.y); o[6] = f2b(b.z); o[7] = f2b(b.w);
    *(u16x8*)(out + i) = o;
}

// cast with zero-padding (for Win padded from 2144 to 2176 rows)
__global__ __launch_bounds__(256) void castpad8(const float* __restrict__ in,
                                                unsigned short* __restrict__ out,
                                                int n, int npad) {
    int i = (blockIdx.x * blockDim.x + threadIdx.x) * 8;
    if (i >= npad) return;
    u16x8 o;
    if (i + 8 <= n) {
        float4 a = *(const float4*)(in + i);
        float4 b = *(const float4*)(in + i + 4);
        o[0] = f2b(a.x); o[1] = f2b(a.y); o[2] = f2b(a.z); o[3] = f2b(a.w);
        o[4] = f2b(b.x); o[5] = f2b(b.y); o[6] = f2b(b.z); o[7] = f2b(b.w);
    } else {
        #pragma unroll
        for (int j = 0; j < 8; ++j) o[j] = (i + j < n) ? f2b(in[i + j]) : (unsigned short)0;
    }
    *(u16x8*)(out + i) = o;
}

// ---- bf16 MFMA GEMM: C[M,N] = A[M,K] @ B[N,K]^T ----
// 128x128 tile, 256 threads (4 waves, 2x2 of 64x64), BK=32, global_load_lds staging.
// B must have >= ceil(N/128)*128 valid rows (pad with zeros). C stores guarded by Nout.
__global__ __launch_bounds__(256) void gemm_mfma(const unsigned short* __restrict__ A,
                                                 const unsigned short* __restrict__ B,
                                                 float* __restrict__ C,
                                                 int Nout, int K) {
    __shared__ unsigned short As[128 * 32];
    __shared__ unsigned short Bs[128 * 32];
    const int t    = threadIdx.x;
    const int wave = t >> 6;
    const int lane = t & 63;
    const int bm   = blockIdx.y * 128;
    const int bn   = blockIdx.x * 128;
    const int wr   = wave >> 1;
    const int wc   = wave & 1;

    // staging source coords (per lane)
    const int srow = wave * 16 + (lane >> 2);
    const int scol = (lane & 3) * 8;
    const unsigned short* ga0 = A + (size_t)(bm + srow) * K + scol;
    const unsigned short* ga1 = A + (size_t)(bm + 64 + srow) * K + scol;
    const unsigned short* gb0 = B + (size_t)(bn + srow) * K + scol;
    const unsigned short* gb1 = B + (size_t)(bn + 64 + srow) * K + scol;
    unsigned short* la0 = &As[wave * 512];
    unsigned short* la1 = &As[2048 + wave * 512];
    unsigned short* lb0 = &Bs[wave * 512];
    unsigned short* lb1 = &Bs[2048 + wave * 512];

    const int fr = lane & 15;
    const int kb = (lane >> 4) * 8;

    f32x4 acc[4][4] = {};

    for (int k0 = 0; k0 < K; k0 += 32) {
        load_lds16(ga0 + k0, la0);
        load_lds16(ga1 + k0, la1);
        load_lds16(gb0 + k0, lb0);
        load_lds16(gb1 + k0, lb1);
        __syncthreads();
        bf16x8 af[4], bfr[4];
        #pragma unroll
        for (int m = 0; m < 4; ++m)
            af[m] = *reinterpret_cast<const bf16x8*>(&As[(wr * 64 + m * 16 + fr) * 32 + kb]);
        #pragma unroll
        for (int n = 0; n < 4; ++n)
            bfr[n] = *reinterpret_cast<const bf16x8*>(&Bs[(wc * 64 + n * 16 + fr) * 32 + kb]);
        #pragma unroll
        for (int m = 0; m < 4; ++m)
            #pragma unroll
            for (int n = 0; n < 4; ++n)
                acc[m][n] = __builtin_amdgcn_mfma_f32_16x16x32_bf16(af[m], bfr[n], acc[m][n], 0, 0, 0);
        __syncthreads();
    }

    const int cr0 = bm + wr * 64 + ((lane >> 4) << 2);
    const int cc0 = bn + wc * 64 + (lane & 15);
    #pragma unroll
    for (int m = 0; m < 4; ++m) {
        #pragma unroll
        for (int n = 0; n < 4; ++n) {
            int col = cc0 + n * 16;
            if (col < Nout) {
                #pragma unroll
                for (int j = 0; j < 4; ++j)
                    C[(size_t)(cr0 + m * 16 + j) * Nout + col] = acc[m][n][j];
            }
        }
    }
}

// depthwise causal conv(4) + bias + SiLU over the xBC slice of zxbcdt
__global__ void conv_silu(const float* __restrict__ zx, const float* __restrict__ cw,
                          const float* __restrict__ cb, float* __restrict__ xc) {
    int idx = blockIdx.x * blockDim.x + threadIdx.x;
    if (idx >= ROWS * CONV_DIM) return;
    int c  = idx % CONV_DIM;
    int bl = idx / CONV_DIM;
    int l  = bl % SEQ;
    float w0 = cw[c * 4 + 0], w1 = cw[c * 4 + 1], w2 = cw[c * 4 + 2], w3 = cw[c * 4 + 3];
    const float* base = zx + (size_t)bl * D_IN_PROJ + D_INNER + c;
    float acc = cb[c];
    if (l >= 3) acc += w0 * base[-3 * D_IN_PROJ];
    if (l >= 2) acc += w1 * base[-2 * D_IN_PROJ];
    if (l >= 1) acc += w2 * base[-1 * D_IN_PROJ];
    acc += w3 * base[0];
    xc[idx] = siluf(acc);
}

__global__ void dt_softplus(const float* __restrict__ zx, const float* __restrict__ dtb,
                            float* __restrict__ dtsp) {
    int idx = blockIdx.x * blockDim.x + threadIdx.x;
    if (idx >= ROWS * NHEADS) return;
    int h  = idx & 63;
    int bl = idx >> 6;
    dtsp[idx] = softplusf(zx[(size_t)bl * D_IN_PROJ + (D_INNER + CONV_DIM) + h] + dtb[h]);
}

// per (b, chunk, head) block: intra-chunk Y_diag + end-of-chunk state
__global__ __launch_bounds__(256) void ssd_chunk(const float* __restrict__ xc,
                                                 const float* __restrict__ dtsp,
                                                 const float* __restrict__ A_log,
                                                 float* __restrict__ ypre,
                                                 float* __restrict__ states,
                                                 float* __restrict__ csb,
                                                 float* __restrict__ csum) {
    __shared__ float Bs[256][16];
    __shared__ float Cs[256][16];
    __shared__ float Xs[256][16];
    __shared__ float cs[256];
    __shared__ float dec[256];
    const int bid = blockIdx.x;
    const int h = bid & 63;
    const int c = (bid >> 6) & 15;
    const int b = bid >> 10;
    const int t = threadIdx.x;
    const int row = b * SEQ + c * CHUNK + t;

    float Ah  = -expf(A_log[h]);
    float dtv = dtsp[(size_t)row * NHEADS + h];
    float dAv = dtv * Ah;
    cs[t] = dAv;
    __syncthreads();
    for (int off = 1; off < 256; off <<= 1) {
        float v = (t >= off) ? cs[t - off] : 0.f;
        __syncthreads();
        cs[t] += v;
        __syncthreads();
    }
    const float* xrow = xc + (size_t)row * CONV_DIM;
    #pragma unroll
    for (int n = 0; n < 16; n += 4) {
        float4 bv = *(const float4*)(xrow + D_INNER + n);
        Bs[t][n] = bv.x; Bs[t][n + 1] = bv.y; Bs[t][n + 2] = bv.z; Bs[t][n + 3] = bv.w;
        float4 cv = *(const float4*)(xrow + D_INNER + D_STATE + n);
        Cs[t][n] = cv.x; Cs[t][n + 1] = cv.y; Cs[t][n + 2] = cv.z; Cs[t][n + 3] = cv.w;
        float4 xv = *(const float4*)(xrow + h * HEADDIM + n);
        Xs[t][n] = xv.x * dtv; Xs[t][n + 1] = xv.y * dtv;
        Xs[t][n + 2] = xv.z * dtv; Xs[t][n + 3] = xv.w * dtv;
    }
    float cl = cs[255];
    dec[t] = expf(cl - cs[t]);
    __syncthreads();

    // Y_diag row t
    float acc[16] = {};
    float cst = cs[t];
    float Ct[16];
    #pragma unroll
    for (int n = 0; n < 16; ++n) Ct[n] = Cs[t][n];
    for (int s = 0; s <= t; ++s) {
        float dot = 0.f;
        #pragma unroll
        for (int n = 0; n < 16; ++n) dot += Ct[n] * Bs[s][n];
        float w = dot * expf(cst - cs[s]);
        #pragma unroll
        for (int p = 0; p < 16; ++p) acc[p] += w * Xs[s][p];
    }
    float* yrow = ypre + (size_t)row * D_INNER + h * HEADDIM;
    #pragma unroll
    for (int p = 0; p < 16; ++p) yrow[p] = acc[p];

    // end-of-chunk state: thread t -> (p = t/16, n = t%16)
    const int p = t >> 4, n = t & 15;
    float st = 0.f;
    for (int s = 0; s < 256; ++s) st += dec[s] * Bs[s][n] * Xs[s][p];
    states[(size_t)bid * 256 + t] = st;
    csb[(size_t)bid * 256 + t] = cs[t];
    if (t == 255) csum[(b * 64 + h) * 16 + c] = cl;
}

// sequential inter-chunk recurrence (tiny): prev_state per chunk
__global__ __launch_bounds__(256) void ssd_rec(const float* __restrict__ states,
                                               const float* __restrict__ csum,
                                               float* __restrict__ prevst) {
    const int bh = blockIdx.x;       // b*64 + h
    const int b = bh >> 6, h = bh & 63;
    const int t = threadIdx.x;
    float run = 0.f;
    for (int c = 0; c < NCHUNK; ++c) {
        size_t idx = ((size_t)((b * 16 + c) * 64 + h)) * 256 + t;
        prevst[idx] = run;
        run = run * expf(csum[bh * 16 + c]) + states[idx];
    }
}

// Y_off + D skip + SiLU(z) gating
__global__ __launch_bounds__(256) void ssd_off(const float* __restrict__ xc,
                                               const float* __restrict__ zx,
                                               const float* __restrict__ prevst,
                                               const float* __restrict__ csb,
                                               const float* __restrict__ Dskip,
                                               float* __restrict__ ypre) {
    __shared__ float ps[256];
    const int bid = blockIdx.x;
    const int h = bid & 63;
    const int c = (bid >> 6) & 15;
    const int b = bid >> 10;
    const int t = threadIdx.x;
    ps[t] = prevst[(size_t)bid * 256 + t];
    __syncthreads();
    const int row = b * SEQ + c * CHUNK + t;
    float sdo = expf(csb[(size_t)bid * 256 + t]);
    const float* xrow = xc + (size_t)row * CONV_DIM;
    float Ct[16];
    #pragma unroll
    for (int n = 0; n < 16; ++n) Ct[n] = xrow[D_INNER + D_STATE + n];
    float d = Dskip[h];
    float* yrow = ypre + (size_t)row * D_INNER + h * HEADDIM;
    const float* zrow = zx + (size_t)row * D_IN_PROJ + h * HEADDIM;
    #pragma unroll
    for (int p = 0; p < 16; ++p) {
        float off = 0.f;
        #pragma unroll
        for (int n = 0; n < 16; ++n) off += Ct[n] * ps[p * 16 + n];
        float yv = yrow[p] + sdo * off + xrow[h * HEADDIM + p] * d;
        float z = zrow[p];
        yrow[p] = yv * siluf(z);
    }
}

// RMSNorm + direct bf16 emit for the out_proj GEMM
__global__ __launch_bounds__(256) void rmsnorm_bf16(const float* __restrict__ y,
                                                    const float* __restrict__ w,
                                                    unsigned short* __restrict__ out) {
    __shared__ float red[4];
    __shared__ float stot;
    const int row = blockIdx.x;
    const int t = threadIdx.x;
    const float* yr = y + (size_t)row * D_INNER;
    float4 v = *(const float4*)(yr + t * 4);
    float ss = v.x * v.x + v.y * v.y + v.z * v.z + v.w * v.w;
    for (int off = 32; off > 0; off >>= 1) ss += __shfl_down(ss, off, 64);
    if ((t & 63) == 0) red[t >> 6] = ss;
    __syncthreads();
    if (t == 0) stot = red[0] + red[1] + red[2] + red[3];
    __syncthreads();
    float rstd = rsqrtf(stot / (float)D_INNER + 1e-5f);
    float4 wv = *(const float4*)(w + t * 4);
    ushort4 o;
    o.x = f2b(v.x * rstd * wv.x);
    o.y = f2b(v.y * rstd * wv.y);
    o.z = f2b(v.z * rstd * wv.z);
    o.w = f2b(v.w * rstd * wv.w);
    *(ushort4*)(out + (size_t)row * D_INNER + t * 4) = o;
}

extern "C" void kernel_launch(void* const* d_in, const int* in_sizes, int n_in,
                              void* d_out, int out_size, void* d_ws, size_t ws_size,
                              hipStream_t stream) {
    const float* u     = (const float*)d_in[0];
    const float* Win   = (const float*)d_in[1];
    const float* cw    = (const float*)d_in[2];
    const float* cb    = (const float*)d_in[3];
    const float* dtb   = (const float*)d_in[4];
    const float* Alog  = (const float*)d_in[5];
    const float* Dsk   = (const float*)d_in[6];
    const float* normw = (const float*)d_in[7];
    const float* Wout  = (const float*)d_in[8];
    float* out = (float*)d_out;

    float* ws   = (float*)d_ws;
    float* zx   = ws;                   // 8192*2144 = 17563648 fp32
    float* xc   = zx + 17563648;        // 8192*1056 = 8650752
    float* dtsp = xc + 8650752;         // 524288
    float* csb  = dtsp + 524288;        // 524288
    float* st   = csb + 524288;         // 524288
    float* pst  = st + 524288;          // 524288
    float* csum = pst + 524288;         // 2048
    float* ypre = csum + 2048;          // 8388608
    float* wob  = ypre + 8388608;       // 262144 fp32 slots for Wout bf16

    // bf16 aliases: u_bf + Win_bf live in ypre region (dead until ssd_chunk);
    // normalized activations live in zx region (dead after ssd_off).
    unsigned short* u_bf    = (unsigned short*)ypre;                 // 4,194,304 bf16
    unsigned short* win_bf  = (unsigned short*)(ypre + 2097152);     // 1,114,112 bf16 (2176x512)
    unsigned short* wout_bf = (unsigned short*)wob;                  // 524,288 bf16
    unsigned short* yn_bf   = (unsigned short*)zx;                   // 8,388,608 bf16

    cast8<<<2048, 256, 0, stream>>>(u, u_bf, 4194304);
    castpad8<<<544, 256, 0, stream>>>(Win, win_bf, 2144 * 512, 2176 * 512);
    cast8<<<256, 256, 0, stream>>>(Wout, wout_bf, 524288);

    gemm_mfma<<<dim3(17, 64), 256, 0, stream>>>(u_bf, win_bf, zx, D_IN_PROJ, D_MODEL);

    conv_silu<<<(ROWS * CONV_DIM + 255) / 256, 256, 0, stream>>>(zx, cw, cb, xc);
    dt_softplus<<<(ROWS * NHEADS) / 256, 256, 0, stream>>>(zx, dtb, dtsp);
    ssd_chunk<<<BATCH * NCHUNK * NHEADS, 256, 0, stream>>>(xc, dtsp, Alog, ypre, st, csb, csum);
    ssd_rec<<<BATCH * NHEADS, 256, 0, stream>>>(st, csum, pst);
    ssd_off<<<BATCH * NCHUNK * NHEADS, 256, 0, stream>>>(xc, zx, pst, csb, Dsk, ypre);
    rmsnorm_bf16<<<ROWS, 256, 0, stream>>>(ypre, normw, yn_bf);

    gemm_mfma<<<dim3(4, 64), 256, 0, stream>>>(yn_bf, wout_bf, out, D_MODEL, D_INNER);
}

// Round 3
// 315.514 us; speedup vs baseline: 2.2532x; 1.2391x over previous
//
#include <hip/hip_runtime.h>
#include <hip/hip_bf16.h>
#include <math.h>

#define D_MODEL   512
#define D_INNER   1024
#define NHEADS    64
#define HEADDIM   16
#define D_STATE   16
#define CONV_DIM  1056
#define D_IN_PROJ 2144
#define CHUNK     256
#define NCHUNK    16
#define BATCH     2
#define SEQ       4096
#define ROWS      (BATCH * SEQ)   // 8192

typedef __bf16    bf16x8 __attribute__((ext_vector_type(8)));
typedef _Float16  f16x8  __attribute__((ext_vector_type(8)));
typedef float     f32x4  __attribute__((ext_vector_type(4)));
typedef unsigned short u16x8 __attribute__((ext_vector_type(8)));

__device__ __forceinline__ float softplusf(float x) {
    return (x > 20.f) ? x : log1pf(expf(x));
}
__device__ __forceinline__ float siluf(float x) {
    return x / (1.f + expf(-x));
}
__device__ __forceinline__ unsigned short f2b(float x) {
    union { __hip_bfloat16 h; unsigned short u; } cv;
    cv.h = __float2bfloat16(x);
    return cv.u;
}
__device__ __forceinline__ void load_lds16(const unsigned short* g, unsigned short* l) {
    __builtin_amdgcn_global_load_lds(
        (const __attribute__((address_space(1))) void*)g,
        (__attribute__((address_space(3))) void*)l,
        16, 0, 0);
}

// ---- cast fp32 -> bf16 (8 elems/thread, 16B stores) ----
__global__ __launch_bounds__(256) void cast8(const float* __restrict__ in,
                                             unsigned short* __restrict__ out, int n) {
    int i = (blockIdx.x * blockDim.x + threadIdx.x) * 8;
    if (i >= n) return;
    float4 a = *(const float4*)(in + i);
    float4 b = *(const float4*)(in + i + 4);
    u16x8 o;
    o[0] = f2b(a.x); o[1] = f2b(a.y); o[2] = f2b(a.z); o[3] = f2b(a.w);
    o[4] = f2b(b.x); o[5] = f2b(b.y); o[6] = f2b(b.z); o[7] = f2b(b.w);
    *(u16x8*)(out + i) = o;
}

__global__ __launch_bounds__(256) void castpad8(const float* __restrict__ in,
                                                unsigned short* __restrict__ out,
                                                int n, int npad) {
    int i = (blockIdx.x * blockDim.x + threadIdx.x) * 8;
    if (i >= npad) return;
    u16x8 o;
    if (i + 8 <= n) {
        float4 a = *(const float4*)(in + i);
        float4 b = *(const float4*)(in + i + 4);
        o[0] = f2b(a.x); o[1] = f2b(a.y); o[2] = f2b(a.z); o[3] = f2b(a.w);
        o[4] = f2b(b.x); o[5] = f2b(b.y); o[6] = f2b(b.z); o[7] = f2b(b.w);
    } else {
        #pragma unroll
        for (int j = 0; j < 8; ++j) o[j] = (i + j < n) ? f2b(in[i + j]) : (unsigned short)0;
    }
    *(u16x8*)(out + i) = o;
}

// ---- bf16 MFMA GEMM: C[M,N] = A[M,K] @ B[N,K]^T ----
__global__ __launch_bounds__(256) void gemm_mfma(const unsigned short* __restrict__ A,
                                                 const unsigned short* __restrict__ B,
                                                 float* __restrict__ C,
                                                 int Nout, int K) {
    __shared__ unsigned short As[128 * 32];
    __shared__ unsigned short Bs[128 * 32];
    const int t    = threadIdx.x;
    const int wave = t >> 6;
    const int lane = t & 63;
    const int bm   = blockIdx.y * 128;
    const int bn   = blockIdx.x * 128;
    const int wr   = wave >> 1;
    const int wc   = wave & 1;

    const int srow = wave * 16 + (lane >> 2);
    const int scol = (lane & 3) * 8;
    const unsigned short* ga0 = A + (size_t)(bm + srow) * K + scol;
    const unsigned short* ga1 = A + (size_t)(bm + 64 + srow) * K + scol;
    const unsigned short* gb0 = B + (size_t)(bn + srow) * K + scol;
    const unsigned short* gb1 = B + (size_t)(bn + 64 + srow) * K + scol;
    unsigned short* la0 = &As[wave * 512];
    unsigned short* la1 = &As[2048 + wave * 512];
    unsigned short* lb0 = &Bs[wave * 512];
    unsigned short* lb1 = &Bs[2048 + wave * 512];

    const int fr = lane & 15;
    const int kb = (lane >> 4) * 8;

    f32x4 acc[4][4] = {};

    for (int k0 = 0; k0 < K; k0 += 32) {
        load_lds16(ga0 + k0, la0);
        load_lds16(ga1 + k0, la1);
        load_lds16(gb0 + k0, lb0);
        load_lds16(gb1 + k0, lb1);
        __syncthreads();
        bf16x8 af[4], bfr[4];
        #pragma unroll
        for (int m = 0; m < 4; ++m)
            af[m] = *reinterpret_cast<const bf16x8*>(&As[(wr * 64 + m * 16 + fr) * 32 + kb]);
        #pragma unroll
        for (int n = 0; n < 4; ++n)
            bfr[n] = *reinterpret_cast<const bf16x8*>(&Bs[(wc * 64 + n * 16 + fr) * 32 + kb]);
        #pragma unroll
        for (int m = 0; m < 4; ++m)
            #pragma unroll
            for (int n = 0; n < 4; ++n)
                acc[m][n] = __builtin_amdgcn_mfma_f32_16x16x32_bf16(af[m], bfr[n], acc[m][n], 0, 0, 0);
        __syncthreads();
    }

    const int cr0 = bm + wr * 64 + ((lane >> 4) << 2);
    const int cc0 = bn + wc * 64 + (lane & 15);
    #pragma unroll
    for (int m = 0; m < 4; ++m) {
        #pragma unroll
        for (int n = 0; n < 4; ++n) {
            int col = cc0 + n * 16;
            if (col < Nout) {
                #pragma unroll
                for (int j = 0; j < 4; ++j)
                    C[(size_t)(cr0 + m * 16 + j) * Nout + col] = acc[m][n][j];
            }
        }
    }
}

// depthwise causal conv(4) + bias + SiLU, 4 channels/thread
__global__ void conv_silu4(const float* __restrict__ zx, const float* __restrict__ cw,
                           const float* __restrict__ cb, float* __restrict__ xc) {
    int idx = blockIdx.x * blockDim.x + threadIdx.x;
    if (idx >= ROWS * (CONV_DIM / 4)) return;
    int cq = idx % (CONV_DIM / 4);
    int bl = idx / (CONV_DIM / 4);
    int l  = bl % SEQ;
    int c4 = cq * 4;
    const float* base = zx + (size_t)bl * D_IN_PROJ + D_INNER + c4;
    float4 w0 = *(const float4*)(cw + (c4 + 0) * 4);
    float4 w1 = *(const float4*)(cw + (c4 + 1) * 4);
    float4 w2 = *(const float4*)(cw + (c4 + 2) * 4);
    float4 w3 = *(const float4*)(cw + (c4 + 3) * 4);
    float4 zf = make_float4(0.f, 0.f, 0.f, 0.f);
    float4 x3 = (l >= 3) ? *(const float4*)(base - 3 * D_IN_PROJ) : zf;
    float4 x2 = (l >= 2) ? *(const float4*)(base - 2 * D_IN_PROJ) : zf;
    float4 x1 = (l >= 1) ? *(const float4*)(base - 1 * D_IN_PROJ) : zf;
    float4 x0 = *(const float4*)(base);
    float4 bb = *(const float4*)(cb + c4);
    float4 r;
    r.x = siluf(bb.x + w0.x * x3.x + w0.y * x2.x + w0.z * x1.x + w0.w * x0.x);
    r.y = siluf(bb.y + w1.x * x3.y + w1.y * x2.y + w1.z * x1.y + w1.w * x0.y);
    r.z = siluf(bb.z + w2.x * x3.z + w2.y * x2.z + w2.z * x1.z + w2.w * x0.z);
    r.w = siluf(bb.w + w3.x * x3.w + w3.y * x2.w + w3.z * x1.w + w3.w * x0.w);
    *(float4*)(xc + (size_t)bl * CONV_DIM + c4) = r;
}

__global__ void dt_softplus(const float* __restrict__ zx, const float* __restrict__ dtb,
                            float* __restrict__ dtsp) {
    int idx = blockIdx.x * blockDim.x + threadIdx.x;
    if (idx >= ROWS * NHEADS) return;
    int h  = idx & 63;
    int bl = idx >> 6;
    dtsp[idx] = softplusf(zx[(size_t)bl * D_IN_PROJ + (D_INNER + CONV_DIM) + h] + dtb[h]);
}

// per (b, chunk, head) block: MFMA-based intra-chunk Y_diag + end-of-chunk state
__global__ __launch_bounds__(256) void ssd_chunk(const float* __restrict__ xc,
                                                 const float* __restrict__ dtsp,
                                                 const float* __restrict__ A_log,
                                                 float* __restrict__ ypre,
                                                 float* __restrict__ states,
                                                 float* __restrict__ csb,
                                                 float* __restrict__ csum) {
    __shared__ _Float16 Cb[256][16];
    __shared__ _Float16 Bb[256][16];
    __shared__ _Float16 Xt[16][264];
    __shared__ _Float16 Xdt[16][264];
    __shared__ _Float16 Bt[16][264];
    __shared__ float csL[256];
    __shared__ float wsumL[4];
    __shared__ _Float16 Pw[4][64][32];
    __shared__ float stpart[4][16][16];

    const int bid = blockIdx.x;
    const int h = bid & 63;
    const int c = (bid >> 6) & 15;
    const int b = bid >> 10;
    const int t = threadIdx.x;
    const int wv = t >> 6;
    const int lane = t & 63;
    const int fr = lane & 15;
    const int hi = lane >> 4;
    const int row = b * SEQ + c * CHUNK + t;

    // --- cumsum of dA: wave shuffle scan + cross-wave offsets ---
    float Ah  = -__expf(A_log[h]);
    float dtv = dtsp[(size_t)row * NHEADS + h];
    float val = dtv * Ah;
    #pragma unroll
    for (int off = 1; off < 64; off <<= 1) {
        float o = __shfl_up(val, off, 64);
        if (lane >= off) val += o;
    }
    if (lane == 63) wsumL[wv] = val;
    __syncthreads();
    float pre = 0.f, cl = 0.f;
    #pragma unroll
    for (int w2 = 0; w2 < 4; ++w2) {
        float s = wsumL[w2];
        if (w2 < wv) pre += s;
        cl += s;
    }
    float cst = val + pre;
    csL[t] = cst;
    csb[(size_t)bid * 256 + t] = cst;
    if (t == 0) csum[(b * 64 + h) * 16 + c] = cl;
    float dec_t = __expf(cl - cst);

    // --- stage B, C, X (f16) ---
    const float* xrow = xc + (size_t)row * CONV_DIM;
    float bv[16], cv[16], xv[16];
    #pragma unroll
    for (int n = 0; n < 16; n += 4) {
        *(float4*)&bv[n] = *(const float4*)(xrow + D_INNER + n);
        *(float4*)&cv[n] = *(const float4*)(xrow + D_INNER + D_STATE + n);
        *(float4*)&xv[n] = *(const float4*)(xrow + h * HEADDIM + n);
    }
    {
        f16x8 pk;
        #pragma unroll
        for (int n = 0; n < 8; ++n) pk[n] = (_Float16)cv[n];
        *(f16x8*)&Cb[t][0] = pk;
        #pragma unroll
        for (int n = 0; n < 8; ++n) pk[n] = (_Float16)cv[8 + n];
        *(f16x8*)&Cb[t][8] = pk;
        #pragma unroll
        for (int n = 0; n < 8; ++n) pk[n] = (_Float16)bv[n];
        *(f16x8*)&Bb[t][0] = pk;
        #pragma unroll
        for (int n = 0; n < 8; ++n) pk[n] = (_Float16)bv[8 + n];
        *(f16x8*)&Bb[t][8] = pk;
    }
    #pragma unroll
    for (int n = 0; n < 16; ++n) {
        Bt[n][t] = (_Float16)bv[n];
        float xd = xv[n] * dtv;
        Xt[n][t] = (_Float16)xd;
        Xdt[n][t] = (_Float16)(xd * dec_t);
    }
    __syncthreads();

    // per-m,j row cs values (invariant over sb)
    float cstv[4][4];
    #pragma unroll
    for (int m = 0; m < 4; ++m)
        #pragma unroll
        for (int j = 0; j < 4; ++j)
            cstv[m][j] = csL[wv * 64 + m * 16 + hi * 4 + j];

    const int r0w = wv * 64;
    f32x4 yacc[4] = {};
    const f32x4 zacc = {};

    for (int sb = 0; sb <= 2 * wv + 1; ++sb) {
        // A-frags (C rows) for this wave
        f16x8 af[4];
        if (hi < 2) {
            #pragma unroll
            for (int m = 0; m < 4; ++m)
                af[m] = *(const f16x8*)&Cb[r0w + m * 16 + fr][hi * 8];
        } else {
            #pragma unroll
            for (int m = 0; m < 4; ++m) af[m] = (f16x8){};
        }
        #pragma unroll
        for (int sc = 0; sc < 2; ++sc) {
            const int s0 = sb * 32 + sc * 16;
            f16x8 bf;
            if (hi < 2) bf = *(const f16x8*)&Bb[s0 + fr][hi * 8];
            else        bf = (f16x8){};
            float css = csL[s0 + fr];
            const int scol = s0 + fr;
            #pragma unroll
            for (int m = 0; m < 4; ++m) {
                const int row0 = r0w + m * 16;
                if (s0 <= row0 + 15) {
                    f32x4 sacc = __builtin_amdgcn_mfma_f32_16x16x32_f16(af[m], bf, zacc, 0, 0, 0);
                    #pragma unroll
                    for (int j = 0; j < 4; ++j) {
                        int tr = row0 + hi * 4 + j;
                        float pv = (scol <= tr) ? sacc[j] * __expf(cstv[m][j] - css) : 0.f;
                        Pw[wv][m * 16 + hi * 4 + j][sc * 16 + fr] = (_Float16)pv;
                    }
                } else {
                    #pragma unroll
                    for (int j = 0; j < 4; ++j)
                        Pw[wv][m * 16 + hi * 4 + j][sc * 16 + fr] = (_Float16)0.f;
                }
            }
        }
        // drain LDS writes before cross-lane re-read (same wave, no barrier needed)
        asm volatile("s_waitcnt lgkmcnt(0)" ::: "memory");
        // Y += P(:, sb*32..+31) @ X(sb*32..+31, :)
        f16x8 xf = *(const f16x8*)&Xt[fr][sb * 32 + hi * 8];
        #pragma unroll
        for (int m = 0; m < 4; ++m) {
            f16x8 pa = *(const f16x8*)&Pw[wv][m * 16 + fr][hi * 8];
            yacc[m] = __builtin_amdgcn_mfma_f32_16x16x32_f16(pa, xf, yacc[m], 0, 0, 0);
        }
    }

    // write Y_diag
    const int browbase = b * SEQ + c * CHUNK;
    #pragma unroll
    for (int m = 0; m < 4; ++m) {
        #pragma unroll
        for (int j = 0; j < 4; ++j) {
            int gr = browbase + r0w + m * 16 + hi * 4 + j;
            ypre[(size_t)gr * D_INNER + h * HEADDIM + fr] = yacc[m][j];
        }
    }

    // end-of-chunk state: each wave sums its own 64-s slice
    f32x4 stacc = {};
    #pragma unroll
    for (int kt = 0; kt < 2; ++kt) {
        f16x8 xa = *(const f16x8*)&Xdt[fr][r0w + kt * 32 + hi * 8];
        f16x8 bb2 = *(const f16x8*)&Bt[fr][r0w + kt * 32 + hi * 8];
        stacc = __builtin_amdgcn_mfma_f32_16x16x32_f16(xa, bb2, stacc, 0, 0, 0);
    }
    #pragma unroll
    for (int j = 0; j < 4; ++j)
        stpart[wv][hi * 4 + j][fr] = stacc[j];
    __syncthreads();
    {
        const int p = t >> 4, n = t & 15;
        float st = stpart[0][p][n] + stpart[1][p][n] + stpart[2][p][n] + stpart[3][p][n];
        states[(size_t)bid * 256 + t] = st;
    }
}

// sequential inter-chunk recurrence (tiny): prev_state per chunk
__global__ __launch_bounds__(256) void ssd_rec(const float* __restrict__ states,
                                               const float* __restrict__ csum,
                                               float* __restrict__ prevst) {
    const int bh = blockIdx.x;       // b*64 + h
    const int b = bh >> 6, h = bh & 63;
    const int t = threadIdx.x;
    float run = 0.f;
    for (int c = 0; c < NCHUNK; ++c) {
        size_t idx = ((size_t)((b * 16 + c) * 64 + h)) * 256 + t;
        prevst[idx] = run;
        run = run * expf(csum[bh * 16 + c]) + states[idx];
    }
}

// Y_off + D skip + SiLU(z) gating
__global__ __launch_bounds__(256) void ssd_off(const float* __restrict__ xc,
                                               const float* __restrict__ zx,
                                               const float* __restrict__ prevst,
                                               const float* __restrict__ csb,
                                               const float* __restrict__ Dskip,
                                               float* __restrict__ ypre) {
    __shared__ float ps[256];
    const int bid = blockIdx.x;
    const int h = bid & 63;
    const int c = (bid >> 6) & 15;
    const int b = bid >> 10;
    const int t = threadIdx.x;
    ps[t] = prevst[(size_t)bid * 256 + t];
    __syncthreads();
    const int row = b * SEQ + c * CHUNK + t;
    float sdo = expf(csb[(size_t)bid * 256 + t]);
    const float* xrow = xc + (size_t)row * CONV_DIM;
    float Ct[16];
    #pragma unroll
    for (int n = 0; n < 16; ++n) Ct[n] = xrow[D_INNER + D_STATE + n];
    float d = Dskip[h];
    float* yrow = ypre + (size_t)row * D_INNER + h * HEADDIM;
    const float* zrow = zx + (size_t)row * D_IN_PROJ + h * HEADDIM;
    #pragma unroll
    for (int p = 0; p < 16; ++p) {
        float off = 0.f;
        #pragma unroll
        for (int n = 0; n < 16; ++n) off += Ct[n] * ps[p * 16 + n];
        float yv = yrow[p] + sdo * off + xrow[h * HEADDIM + p] * d;
        float z = zrow[p];
        yrow[p] = yv * siluf(z);
    }
}

// RMSNorm + direct bf16 emit for the out_proj GEMM
__global__ __launch_bounds__(256) void rmsnorm_bf16(const float* __restrict__ y,
                                                    const float* __restrict__ w,
                                                    unsigned short* __restrict__ out) {
    __shared__ float red[4];
    __shared__ float stot;
    const int row = blockIdx.x;
    const int t = threadIdx.x;
    const float* yr = y + (size_t)row * D_INNER;
    float4 v = *(const float4*)(yr + t * 4);
    float ss = v.x * v.x + v.y * v.y + v.z * v.z + v.w * v.w;
    for (int off = 32; off > 0; off >>= 1) ss += __shfl_down(ss, off, 64);
    if ((t & 63) == 0) red[t >> 6] = ss;
    __syncthreads();
    if (t == 0) stot = red[0] + red[1] + red[2] + red[3];
    __syncthreads();
    float rstd = rsqrtf(stot / (float)D_INNER + 1e-5f);
    float4 wv = *(const float4*)(w + t * 4);
    ushort4 o;
    o.x = f2b(v.x * rstd * wv.x);
    o.y = f2b(v.y * rstd * wv.y);
    o.z = f2b(v.z * rstd * wv.z);
    o.w = f2b(v.w * rstd * wv.w);
    *(ushort4*)(out + (size_t)row * D_INNER + t * 4) = o;
}

extern "C" void kernel_launch(void* const* d_in, const int* in_sizes, int n_in,
                              void* d_out, int out_size, void* d_ws, size_t ws_size,
                              hipStream_t stream) {
    const float* u     = (const float*)d_in[0];
    const float* Win   = (const float*)d_in[1];
    const float* cw    = (const float*)d_in[2];
    const float* cb    = (const float*)d_in[3];
    const float* dtb   = (const float*)d_in[4];
    const float* Alog  = (const float*)d_in[5];
    const float* Dsk   = (const float*)d_in[6];
    const float* normw = (const float*)d_in[7];
    const float* Wout  = (const float*)d_in[8];
    float* out = (float*)d_out;

    float* ws   = (float*)d_ws;
    float* zx   = ws;                   // 8192*2144 fp32
    float* xc   = zx + 17563648;        // 8192*1056
    float* dtsp = xc + 8650752;         // 524288
    float* csb  = dtsp + 524288;        // 524288
    float* st   = csb + 524288;         // 524288
    float* pst  = st + 524288;          // 524288
    float* csum = pst + 524288;         // 2048
    float* ypre = csum + 2048;          // 8388608
    float* wob  = ypre + 8388608;       // 262144

    unsigned short* u_bf    = (unsigned short*)ypre;
    unsigned short* win_bf  = (unsigned short*)(ypre + 2097152);
    unsigned short* wout_bf = (unsigned short*)wob;
    unsigned short* yn_bf   = (unsigned short*)zx;

    cast8<<<2048, 256, 0, stream>>>(u, u_bf, 4194304);
    castpad8<<<544, 256, 0, stream>>>(Win, win_bf, 2144 * 512, 2176 * 512);
    cast8<<<256, 256, 0, stream>>>(Wout, wout_bf, 524288);

    gemm_mfma<<<dim3(17, 64), 256, 0, stream>>>(u_bf, win_bf, zx, D_IN_PROJ, D_MODEL);

    conv_silu4<<<(ROWS * (CONV_DIM / 4)) / 256, 256, 0, stream>>>(zx, cw, cb, xc);
    dt_softplus<<<(ROWS * NHEADS) / 256, 256, 0, stream>>>(zx, dtb, dtsp);
    ssd_chunk<<<BATCH * NCHUNK * NHEADS, 256, 0, stream>>>(xc, dtsp, Alog, ypre, st, csb, csum);
    ssd_rec<<<BATCH * NHEADS, 256, 0, stream>>>(st, csum, pst);
    ssd_off<<<BATCH * NCHUNK * NHEADS, 256, 0, stream>>>(xc, zx, pst, csb, Dsk, ypre);
    rmsnorm_bf16<<<ROWS, 256, 0, stream>>>(ypre, normw, yn_bf);

    gemm_mfma<<<dim3(4, 64), 256, 0, stream>>>(yn_bf, wout_bf, out, D_MODEL, D_INNER);
}

// Round 4
// 226.136 us; speedup vs baseline: 3.1438x; 1.3952x over previous
//
#include <hip/hip_runtime.h>
#include <hip/hip_bf16.h>
#include <math.h>

#define D_MODEL   512
#define D_INNER   1024
#define NHEADS    64
#define HEADDIM   16
#define D_STATE   16
#define CONV_DIM  1056
#define D_IN_PROJ 2144
#define CHUNK     256
#define NCHUNK    16
#define BATCH     2
#define SEQ       4096
#define ROWS      (BATCH * SEQ)   // 8192

typedef __bf16    bf16x8 __attribute__((ext_vector_type(8)));
typedef _Float16  f16x8  __attribute__((ext_vector_type(8)));
typedef float     f32x4  __attribute__((ext_vector_type(4)));
typedef unsigned short u16x8 __attribute__((ext_vector_type(8)));

__device__ __forceinline__ float softplusf(float x) {
    return (x > 20.f) ? x : log1pf(expf(x));
}
__device__ __forceinline__ float siluf(float x) {
    return x / (1.f + expf(-x));
}
__device__ __forceinline__ unsigned short f2b(float x) {
    union { __hip_bfloat16 h; unsigned short u; } cv;
    cv.h = __float2bfloat16(x);
    return cv.u;
}
__device__ __forceinline__ void load_lds16(const unsigned short* g, unsigned short* l) {
    __builtin_amdgcn_global_load_lds(
        (const __attribute__((address_space(1))) void*)g,
        (__attribute__((address_space(3))) void*)l,
        16, 0, 0);
}

// ---- cast fp32 -> bf16 ----
__global__ __launch_bounds__(256) void cast8(const float* __restrict__ in,
                                             unsigned short* __restrict__ out, int n) {
    int i = (blockIdx.x * blockDim.x + threadIdx.x) * 8;
    if (i >= n) return;
    float4 a = *(const float4*)(in + i);
    float4 b = *(const float4*)(in + i + 4);
    u16x8 o;
    o[0] = f2b(a.x); o[1] = f2b(a.y); o[2] = f2b(a.z); o[3] = f2b(a.w);
    o[4] = f2b(b.x); o[5] = f2b(b.y); o[6] = f2b(b.z); o[7] = f2b(b.w);
    *(u16x8*)(out + i) = o;
}

__global__ __launch_bounds__(256) void castpad8(const float* __restrict__ in,
                                                unsigned short* __restrict__ out,
                                                int n, int npad) {
    int i = (blockIdx.x * blockDim.x + threadIdx.x) * 8;
    if (i >= npad) return;
    u16x8 o;
    if (i + 8 <= n) {
        float4 a = *(const float4*)(in + i);
        float4 b = *(const float4*)(in + i + 4);
        o[0] = f2b(a.x); o[1] = f2b(a.y); o[2] = f2b(a.z); o[3] = f2b(a.w);
        o[4] = f2b(b.x); o[5] = f2b(b.y); o[6] = f2b(b.z); o[7] = f2b(b.w);
    } else {
        #pragma unroll
        for (int j = 0; j < 8; ++j) o[j] = (i + j < n) ? f2b(in[i + j]) : (unsigned short)0;
    }
    *(u16x8*)(out + i) = o;
}

// ---- bf16 MFMA GEMM: C[M,N] = A[M,K](lda) @ B[N,K]^T ----
__global__ __launch_bounds__(256) void gemm_mfma(const unsigned short* __restrict__ A,
                                                 const unsigned short* __restrict__ B,
                                                 float* __restrict__ C,
                                                 int Nout, int K, int lda) {
    __shared__ unsigned short As[128 * 32];
    __shared__ unsigned short Bs[128 * 32];
    const int t    = threadIdx.x;
    const int wave = t >> 6;
    const int lane = t & 63;
    const int bm   = blockIdx.y * 128;
    const int bn   = blockIdx.x * 128;
    const int wr   = wave >> 1;
    const int wc   = wave & 1;

    const int srow = wave * 16 + (lane >> 2);
    const int scol = (lane & 3) * 8;
    const unsigned short* ga0 = A + (size_t)(bm + srow) * lda + scol;
    const unsigned short* ga1 = A + (size_t)(bm + 64 + srow) * lda + scol;
    const unsigned short* gb0 = B + (size_t)(bn + srow) * K + scol;
    const unsigned short* gb1 = B + (size_t)(bn + 64 + srow) * K + scol;
    unsigned short* la0 = &As[wave * 512];
    unsigned short* la1 = &As[2048 + wave * 512];
    unsigned short* lb0 = &Bs[wave * 512];
    unsigned short* lb1 = &Bs[2048 + wave * 512];

    const int fr = lane & 15;
    const int kb = (lane >> 4) * 8;

    f32x4 acc[4][4] = {};

    for (int k0 = 0; k0 < K; k0 += 32) {
        load_lds16(ga0 + k0, la0);
        load_lds16(ga1 + k0, la1);
        load_lds16(gb0 + k0, lb0);
        load_lds16(gb1 + k0, lb1);
        __syncthreads();
        bf16x8 af[4], bfr[4];
        #pragma unroll
        for (int m = 0; m < 4; ++m)
            af[m] = *reinterpret_cast<const bf16x8*>(&As[(wr * 64 + m * 16 + fr) * 32 + kb]);
        #pragma unroll
        for (int n = 0; n < 4; ++n)
            bfr[n] = *reinterpret_cast<const bf16x8*>(&Bs[(wc * 64 + n * 16 + fr) * 32 + kb]);
        #pragma unroll
        for (int m = 0; m < 4; ++m)
            #pragma unroll
            for (int n = 0; n < 4; ++n)
                acc[m][n] = __builtin_amdgcn_mfma_f32_16x16x32_bf16(af[m], bfr[n], acc[m][n], 0, 0, 0);
        __syncthreads();
    }

    const int cr0 = bm + wr * 64 + ((lane >> 4) << 2);
    const int cc0 = bn + wc * 64 + (lane & 15);
    #pragma unroll
    for (int m = 0; m < 4; ++m) {
        #pragma unroll
        for (int n = 0; n < 4; ++n) {
            int col = cc0 + n * 16;
            if (col < Nout) {
                #pragma unroll
                for (int j = 0; j < 4; ++j)
                    C[(size_t)(cr0 + m * 16 + j) * Nout + col] = acc[m][n][j];
            }
        }
    }
}

// depthwise causal conv(4) + bias + SiLU, 4 channels/thread
__global__ void conv_silu4(const float* __restrict__ zx, const float* __restrict__ cw,
                           const float* __restrict__ cb, float* __restrict__ xc) {
    int idx = blockIdx.x * blockDim.x + threadIdx.x;
    if (idx >= ROWS * (CONV_DIM / 4)) return;
    int cq = idx % (CONV_DIM / 4);
    int bl = idx / (CONV_DIM / 4);
    int l  = bl % SEQ;
    int c4 = cq * 4;
    const float* base = zx + (size_t)bl * D_IN_PROJ + D_INNER + c4;
    float4 w0 = *(const float4*)(cw + (c4 + 0) * 4);
    float4 w1 = *(const float4*)(cw + (c4 + 1) * 4);
    float4 w2 = *(const float4*)(cw + (c4 + 2) * 4);
    float4 w3 = *(const float4*)(cw + (c4 + 3) * 4);
    float4 zf = make_float4(0.f, 0.f, 0.f, 0.f);
    float4 x3 = (l >= 3) ? *(const float4*)(base - 3 * D_IN_PROJ) : zf;
    float4 x2 = (l >= 2) ? *(const float4*)(base - 2 * D_IN_PROJ) : zf;
    float4 x1 = (l >= 1) ? *(const float4*)(base - 1 * D_IN_PROJ) : zf;
    float4 x0 = *(const float4*)(base);
    float4 bb = *(const float4*)(cb + c4);
    float4 r;
    r.x = siluf(bb.x + w0.x * x3.x + w0.y * x2.x + w0.z * x1.x + w0.w * x0.x);
    r.y = siluf(bb.y + w1.x * x3.y + w1.y * x2.y + w1.z * x1.y + w1.w * x0.y);
    r.z = siluf(bb.z + w2.x * x3.z + w2.y * x2.z + w2.z * x1.z + w2.w * x0.z);
    r.w = siluf(bb.w + w3.x * x3.w + w3.y * x2.w + w3.z * x1.w + w3.w * x0.w);
    *(float4*)(xc + (size_t)bl * CONV_DIM + c4) = r;
}

__global__ void dt_softplus(const float* __restrict__ zx, const float* __restrict__ dtb,
                            float* __restrict__ dtsp) {
    int idx = blockIdx.x * blockDim.x + threadIdx.x;
    if (idx >= ROWS * NHEADS) return;
    int h  = idx & 63;
    int bl = idx >> 6;
    dtsp[idx] = softplusf(zx[(size_t)bl * D_IN_PROJ + (D_INNER + CONV_DIM) + h] + dtb[h]);
}

// per (b, chunk, head) block: MFMA-based intra-chunk Y_diag + end-of-chunk state
__global__ __launch_bounds__(256) void ssd_chunk(const float* __restrict__ xc,
                                                 const float* __restrict__ dtsp,
                                                 const float* __restrict__ A_log,
                                                 float* __restrict__ ypre,
                                                 float* __restrict__ states,
                                                 float* __restrict__ csb,
                                                 float* __restrict__ csum) {
    __shared__ _Float16 Cb[256][16];
    __shared__ _Float16 Bb[256][16];
    __shared__ _Float16 Xt[16][264];
    __shared__ _Float16 Xdt[16][264];
    __shared__ _Float16 Bt[16][264];
    __shared__ float csL[256];
    __shared__ float wsumL[4];
    __shared__ _Float16 Pw[4][64][32];
    __shared__ float stpart[4][16][16];

    const int bid = blockIdx.x;
    const int h = bid & 63;
    const int c = (bid >> 6) & 15;
    const int b = bid >> 10;
    const int t = threadIdx.x;
    const int wv = t >> 6;
    const int lane = t & 63;
    const int fr = lane & 15;
    const int hi = lane >> 4;
    const int row = b * SEQ + c * CHUNK + t;

    float Ah  = -__expf(A_log[h]);
    float dtv = dtsp[(size_t)row * NHEADS + h];
    float val = dtv * Ah;
    #pragma unroll
    for (int off = 1; off < 64; off <<= 1) {
        float o = __shfl_up(val, off, 64);
        if (lane >= off) val += o;
    }
    if (lane == 63) wsumL[wv] = val;
    __syncthreads();
    float pre = 0.f, cl = 0.f;
    #pragma unroll
    for (int w2 = 0; w2 < 4; ++w2) {
        float s = wsumL[w2];
        if (w2 < wv) pre += s;
        cl += s;
    }
    float cst = val + pre;
    csL[t] = cst;
    csb[(size_t)bid * 256 + t] = cst;
    if (t == 0) csum[(b * 64 + h) * 16 + c] = cl;
    float dec_t = __expf(cl - cst);

    const float* xrow = xc + (size_t)row * CONV_DIM;
    float bv[16], cv[16], xv[16];
    #pragma unroll
    for (int n = 0; n < 16; n += 4) {
        *(float4*)&bv[n] = *(const float4*)(xrow + D_INNER + n);
        *(float4*)&cv[n] = *(const float4*)(xrow + D_INNER + D_STATE + n);
        *(float4*)&xv[n] = *(const float4*)(xrow + h * HEADDIM + n);
    }
    {
        f16x8 pk;
        #pragma unroll
        for (int n = 0; n < 8; ++n) pk[n] = (_Float16)cv[n];
        *(f16x8*)&Cb[t][0] = pk;
        #pragma unroll
        for (int n = 0; n < 8; ++n) pk[n] = (_Float16)cv[8 + n];
        *(f16x8*)&Cb[t][8] = pk;
        #pragma unroll
        for (int n = 0; n < 8; ++n) pk[n] = (_Float16)bv[n];
        *(f16x8*)&Bb[t][0] = pk;
        #pragma unroll
        for (int n = 0; n < 8; ++n) pk[n] = (_Float16)bv[8 + n];
        *(f16x8*)&Bb[t][8] = pk;
    }
    #pragma unroll
    for (int n = 0; n < 16; ++n) {
        Bt[n][t] = (_Float16)bv[n];
        float xd = xv[n] * dtv;
        Xt[n][t] = (_Float16)xd;
        Xdt[n][t] = (_Float16)(xd * dec_t);
    }
    __syncthreads();

    float cstv[4][4];
    #pragma unroll
    for (int m = 0; m < 4; ++m)
        #pragma unroll
        for (int j = 0; j < 4; ++j)
            cstv[m][j] = csL[wv * 64 + m * 16 + hi * 4 + j];

    const int r0w = wv * 64;
    f32x4 yacc[4] = {};
    const f32x4 zacc = {};

    for (int sb = 0; sb <= 2 * wv + 1; ++sb) {
        f16x8 af[4];
        if (hi < 2) {
            #pragma unroll
            for (int m = 0; m < 4; ++m)
                af[m] = *(const f16x8*)&Cb[r0w + m * 16 + fr][hi * 8];
        } else {
            #pragma unroll
            for (int m = 0; m < 4; ++m) af[m] = (f16x8){};
        }
        #pragma unroll
        for (int sc = 0; sc < 2; ++sc) {
            const int s0 = sb * 32 + sc * 16;
            f16x8 bf;
            if (hi < 2) bf = *(const f16x8*)&Bb[s0 + fr][hi * 8];
            else        bf = (f16x8){};
            float css = csL[s0 + fr];
            const int scol = s0 + fr;
            #pragma unroll
            for (int m = 0; m < 4; ++m) {
                const int row0 = r0w + m * 16;
                if (s0 <= row0 + 15) {
                    f32x4 sacc = __builtin_amdgcn_mfma_f32_16x16x32_f16(af[m], bf, zacc, 0, 0, 0);
                    #pragma unroll
                    for (int j = 0; j < 4; ++j) {
                        int tr = row0 + hi * 4 + j;
                        float pv = (scol <= tr) ? sacc[j] * __expf(cstv[m][j] - css) : 0.f;
                        Pw[wv][m * 16 + hi * 4 + j][sc * 16 + fr] = (_Float16)pv;
                    }
                } else {
                    #pragma unroll
                    for (int j = 0; j < 4; ++j)
                        Pw[wv][m * 16 + hi * 4 + j][sc * 16 + fr] = (_Float16)0.f;
                }
            }
        }
        asm volatile("s_waitcnt lgkmcnt(0)" ::: "memory");
        f16x8 xf = *(const f16x8*)&Xt[fr][sb * 32 + hi * 8];
        #pragma unroll
        for (int m = 0; m < 4; ++m) {
            f16x8 pa = *(const f16x8*)&Pw[wv][m * 16 + fr][hi * 8];
            yacc[m] = __builtin_amdgcn_mfma_f32_16x16x32_f16(pa, xf, yacc[m], 0, 0, 0);
        }
    }

    const int browbase = b * SEQ + c * CHUNK;
    #pragma unroll
    for (int m = 0; m < 4; ++m) {
        #pragma unroll
        for (int j = 0; j < 4; ++j) {
            int gr = browbase + r0w + m * 16 + hi * 4 + j;
            ypre[(size_t)gr * D_INNER + h * HEADDIM + fr] = yacc[m][j];
        }
    }

    f32x4 stacc = {};
    #pragma unroll
    for (int kt = 0; kt < 2; ++kt) {
        f16x8 xa = *(const f16x8*)&Xdt[fr][r0w + kt * 32 + hi * 8];
        f16x8 bb2 = *(const f16x8*)&Bt[fr][r0w + kt * 32 + hi * 8];
        stacc = __builtin_amdgcn_mfma_f32_16x16x32_f16(xa, bb2, stacc, 0, 0, 0);
    }
    #pragma unroll
    for (int j = 0; j < 4; ++j)
        stpart[wv][hi * 4 + j][fr] = stacc[j];
    __syncthreads();
    {
        const int p = t >> 4, n = t & 15;
        float st = stpart[0][p][n] + stpart[1][p][n] + stpart[2][p][n] + stpart[3][p][n];
        states[(size_t)bid * 256 + t] = st;
    }
}

// sequential inter-chunk recurrence (tiny)
__global__ __launch_bounds__(256) void ssd_rec(const float* __restrict__ states,
                                               const float* __restrict__ csum,
                                               float* __restrict__ prevst) {
    const int bh = blockIdx.x;
    const int b = bh >> 6, h = bh & 63;
    const int t = threadIdx.x;
    float run = 0.f;
    for (int c = 0; c < NCHUNK; ++c) {
        size_t idx = ((size_t)((b * 16 + c) * 64 + h)) * 256 + t;
        prevst[idx] = run;
        run = run * expf(csum[bh * 16 + c]) + states[idx];
    }
}

// Fused: Y_off + D skip + SiLU(z) gating + RMSNorm -> bf16 (strided into zx's dead cols)
// grid: 32 chunks * 16 rowblocks; block 512 threads, 2 channels each, 16 rows.
__global__ __launch_bounds__(512, 4) void ssd_off_norm(const float* __restrict__ xc,
                                                       const float* __restrict__ zx,
                                                       const float* __restrict__ ypre,
                                                       const float* __restrict__ prevst,
                                                       const float* __restrict__ csb,
                                                       const float* __restrict__ Dskip,
                                                       const float* __restrict__ normw,
                                                       unsigned short* __restrict__ yout,
                                                       int ldy) {
    __shared__ float Cs[16][16];
    __shared__ float csS[64][16];
    __shared__ float nw[1024];
    __shared__ float Dn[64];
    __shared__ float red[16][8];

    const int blk = blockIdx.x;
    const int bc = blk >> 4;          // b*16 + c
    const int rb = blk & 15;
    const int r0 = rb * 16;
    const int b = bc >> 4, c = bc & 15;
    const int brow0 = b * SEQ + c * CHUNK;
    const int t = threadIdx.x;
    const int ch0 = t * 2;
    const int h = ch0 >> 4;
    const int p0 = ch0 & 15;
    const int wv = t >> 6;
    const int lane = t & 63;

    // stage norm weights, D, C rows, cs slice
    if (t < 256) *(float4*)&nw[t * 4] = *(const float4*)(normw + t * 4);
    else if (t < 320) Dn[t - 256] = Dskip[t - 256];
    if (t < 64) {
        int r = t >> 2, n4 = (t & 3) * 4;
        *(float4*)&Cs[r][n4] =
            *(const float4*)(xc + (size_t)(brow0 + r0 + r) * CONV_DIM + D_INNER + D_STATE + n4);
    }
    #pragma unroll
    for (int i = t; i < 1024; i += 512) {
        int r = i & 15, hh = i >> 4;
        csS[hh][r] = csb[(size_t)(bc * 64 + hh) * 256 + r0 + r];
    }

    // prev-state for this thread's 2 channels -> registers (reused all 16 rows)
    float ps[2][16];
    {
        const float* pbase = prevst + (size_t)(bc * 64 + h) * 256 + p0 * 16;
        #pragma unroll
        for (int n4 = 0; n4 < 16; n4 += 4) {
            *(float4*)&ps[0][n4] = *(const float4*)(pbase + n4);
            *(float4*)&ps[1][n4] = *(const float4*)(pbase + 16 + n4);
        }
    }
    __syncthreads();

    const float d = Dn[h];
    const float nw0 = nw[ch0], nw1 = nw[ch0 + 1];

    for (int r = 0; r < 16; ++r) {
        const size_t grow = (size_t)(brow0 + r0 + r);
        float2 yv = *(const float2*)(ypre + grow * D_INNER + ch0);
        float2 xv = *(const float2*)(xc + grow * CONV_DIM + ch0);
        float2 zv = *(const float2*)(zx + grow * D_IN_PROJ + ch0);
        float sdo = __expf(csS[h][r]);
        float off0 = 0.f, off1 = 0.f;
        #pragma unroll
        for (int n = 0; n < 16; ++n) {
            float cn = Cs[r][n];
            off0 += cn * ps[0][n];
            off1 += cn * ps[1][n];
        }
        float g0 = (yv.x + sdo * off0 + xv.x * d) * siluf(zv.x);
        float g1 = (yv.y + sdo * off1 + xv.y * d) * siluf(zv.y);
        float s = g0 * g0 + g1 * g1;
        #pragma unroll
        for (int o = 32; o > 0; o >>= 1) s += __shfl_down(s, o, 64);
        if (lane == 0) red[r][wv] = s;
        __syncthreads();
        float tot = 0.f;
        #pragma unroll
        for (int w2 = 0; w2 < 8; ++w2) tot += red[r][w2];
        float rstd = rsqrtf(tot * (1.f / (float)D_INNER) + 1e-5f);
        ushort2 o2;
        o2.x = f2b(g0 * rstd * nw0);
        o2.y = f2b(g1 * rstd * nw1);
        *(ushort2*)(yout + grow * ldy + ch0) = o2;
    }
}

extern "C" void kernel_launch(void* const* d_in, const int* in_sizes, int n_in,
                              void* d_out, int out_size, void* d_ws, size_t ws_size,
                              hipStream_t stream) {
    const float* u     = (const float*)d_in[0];
    const float* Win   = (const float*)d_in[1];
    const float* cw    = (const float*)d_in[2];
    const float* cb    = (const float*)d_in[3];
    const float* dtb   = (const float*)d_in[4];
    const float* Alog  = (const float*)d_in[5];
    const float* Dsk   = (const float*)d_in[6];
    const float* normw = (const float*)d_in[7];
    const float* Wout  = (const float*)d_in[8];
    float* out = (float*)d_out;

    float* ws   = (float*)d_ws;
    float* zx   = ws;                   // 8192*2144 fp32
    float* xc   = zx + 17563648;        // 8192*1056
    float* dtsp = xc + 8650752;         // 524288
    float* csb  = dtsp + 524288;        // 524288
    float* st   = csb + 524288;         // 524288
    float* pst  = st + 524288;          // 524288
    float* csum = pst + 524288;         // 2048
    float* ypre = csum + 2048;          // 8388608
    float* wob  = ypre + 8388608;       // 262144

    unsigned short* u_bf    = (unsigned short*)ypre;
    unsigned short* win_bf  = (unsigned short*)(ypre + 2097152);
    unsigned short* wout_bf = (unsigned short*)wob;
    // normalized bf16 activations live in zx's dead xBC columns:
    // row stride 4288 ushorts (= 2144 fp32), column offset 2176 ushorts (fp32 col 1088)
    unsigned short* yn_bf   = (unsigned short*)zx + 2176;

    cast8<<<2048, 256, 0, stream>>>(u, u_bf, 4194304);
    castpad8<<<544, 256, 0, stream>>>(Win, win_bf, 2144 * 512, 2176 * 512);
    cast8<<<256, 256, 0, stream>>>(Wout, wout_bf, 524288);

    gemm_mfma<<<dim3(17, 64), 256, 0, stream>>>(u_bf, win_bf, zx, D_IN_PROJ, D_MODEL, D_MODEL);

    conv_silu4<<<(ROWS * (CONV_DIM / 4)) / 256, 256, 0, stream>>>(zx, cw, cb, xc);
    dt_softplus<<<(ROWS * NHEADS) / 256, 256, 0, stream>>>(zx, dtb, dtsp);
    ssd_chunk<<<BATCH * NCHUNK * NHEADS, 256, 0, stream>>>(xc, dtsp, Alog, ypre, st, csb, csum);
    ssd_rec<<<BATCH * NHEADS, 256, 0, stream>>>(st, csum, pst);
    ssd_off_norm<<<512, 512, 0, stream>>>(xc, zx, ypre, pst, csb, Dsk, normw, yn_bf, 4288);

    gemm_mfma<<<dim3(4, 64), 256, 0, stream>>>(yn_bf, wout_bf, out, D_MODEL, D_INNER, 4288);
}

// Round 5
// 186.993 us; speedup vs baseline: 3.8019x; 1.2093x over previous
//
#include <hip/hip_runtime.h>
#include <hip/hip_bf16.h>
#include <math.h>

#define D_MODEL   512
#define D_INNER   1024
#define NHEADS    64
#define HEADDIM   16
#define D_STATE   16
#define CONV_DIM  1056
#define D_IN_PROJ 2144
#define CHUNK     256
#define NCHUNK    16
#define BATCH     2
#define SEQ       4096
#define ROWS      (BATCH * SEQ)   // 8192

typedef __bf16    bf16x8 __attribute__((ext_vector_type(8)));
typedef _Float16  f16x8  __attribute__((ext_vector_type(8)));
typedef float     f32x4  __attribute__((ext_vector_type(4)));
typedef float     f32x16 __attribute__((ext_vector_type(16)));
typedef unsigned short u16x8 __attribute__((ext_vector_type(8)));
typedef unsigned int   u32x4 __attribute__((ext_vector_type(4)));

__device__ __forceinline__ float softplusf(float x) {
    return (x > 20.f) ? x : log1pf(expf(x));
}
__device__ __forceinline__ float siluf(float x) {
    return x / (1.f + expf(-x));
}
__device__ __forceinline__ unsigned short f2b(float x) {
    union { __hip_bfloat16 h; unsigned short u; } cv;
    cv.h = __float2bfloat16(x);
    return cv.u;
}
__device__ __forceinline__ void load_lds16(const unsigned short* g, unsigned short* l) {
    __builtin_amdgcn_global_load_lds(
        (const __attribute__((address_space(1))) void*)g,
        (__attribute__((address_space(3))) void*)l,
        16, 0, 0);
}

// ---- cast fp32 -> bf16 ----
__global__ __launch_bounds__(256) void cast8(const float* __restrict__ in,
                                             unsigned short* __restrict__ out, int n) {
    int i = (blockIdx.x * blockDim.x + threadIdx.x) * 8;
    if (i >= n) return;
    float4 a = *(const float4*)(in + i);
    float4 b = *(const float4*)(in + i + 4);
    u16x8 o;
    o[0] = f2b(a.x); o[1] = f2b(a.y); o[2] = f2b(a.z); o[3] = f2b(a.w);
    o[4] = f2b(b.x); o[5] = f2b(b.y); o[6] = f2b(b.z); o[7] = f2b(b.w);
    *(u16x8*)(out + i) = o;
}

__global__ __launch_bounds__(256) void castpad8(const float* __restrict__ in,
                                                unsigned short* __restrict__ out,
                                                int n, int npad) {
    int i = (blockIdx.x * blockDim.x + threadIdx.x) * 8;
    if (i >= npad) return;
    u16x8 o;
    if (i + 8 <= n) {
        float4 a = *(const float4*)(in + i);
        float4 b = *(const float4*)(in + i + 4);
        o[0] = f2b(a.x); o[1] = f2b(a.y); o[2] = f2b(a.z); o[3] = f2b(a.w);
        o[4] = f2b(b.x); o[5] = f2b(b.y); o[6] = f2b(b.z); o[7] = f2b(b.w);
    } else {
        #pragma unroll
        for (int j = 0; j < 8; ++j) o[j] = (i + j < n) ? f2b(in[i + j]) : (unsigned short)0;
    }
    *(u16x8*)(out + i) = o;
}

// ---- bf16 MFMA GEMM: C[M,N] = A[M,K](lda) @ B[N,K]^T ----
__global__ __launch_bounds__(256) void gemm_mfma(const unsigned short* __restrict__ A,
                                                 const unsigned short* __restrict__ B,
                                                 float* __restrict__ C,
                                                 int Nout, int K, int lda) {
    __shared__ unsigned short As[128 * 32];
    __shared__ unsigned short Bs[128 * 32];
    const int t    = threadIdx.x;
    const int wave = t >> 6;
    const int lane = t & 63;
    const int bm   = blockIdx.y * 128;
    const int bn   = blockIdx.x * 128;
    const int wr   = wave >> 1;
    const int wc   = wave & 1;

    const int srow = wave * 16 + (lane >> 2);
    const int scol = (lane & 3) * 8;
    const unsigned short* ga0 = A + (size_t)(bm + srow) * lda + scol;
    const unsigned short* ga1 = A + (size_t)(bm + 64 + srow) * lda + scol;
    const unsigned short* gb0 = B + (size_t)(bn + srow) * K + scol;
    const unsigned short* gb1 = B + (size_t)(bn + 64 + srow) * K + scol;
    unsigned short* la0 = &As[wave * 512];
    unsigned short* la1 = &As[2048 + wave * 512];
    unsigned short* lb0 = &Bs[wave * 512];
    unsigned short* lb1 = &Bs[2048 + wave * 512];

    const int fr = lane & 15;
    const int kb = (lane >> 4) * 8;

    f32x4 acc[4][4] = {};

    for (int k0 = 0; k0 < K; k0 += 32) {
        load_lds16(ga0 + k0, la0);
        load_lds16(ga1 + k0, la1);
        load_lds16(gb0 + k0, lb0);
        load_lds16(gb1 + k0, lb1);
        __syncthreads();
        bf16x8 af[4], bfr[4];
        #pragma unroll
        for (int m = 0; m < 4; ++m)
            af[m] = *reinterpret_cast<const bf16x8*>(&As[(wr * 64 + m * 16 + fr) * 32 + kb]);
        #pragma unroll
        for (int n = 0; n < 4; ++n)
            bfr[n] = *reinterpret_cast<const bf16x8*>(&Bs[(wc * 64 + n * 16 + fr) * 32 + kb]);
        #pragma unroll
        for (int m = 0; m < 4; ++m)
            #pragma unroll
            for (int n = 0; n < 4; ++n)
                acc[m][n] = __builtin_amdgcn_mfma_f32_16x16x32_bf16(af[m], bfr[n], acc[m][n], 0, 0, 0);
        __syncthreads();
    }

    const int cr0 = bm + wr * 64 + ((lane >> 4) << 2);
    const int cc0 = bn + wc * 64 + (lane & 15);
    #pragma unroll
    for (int m = 0; m < 4; ++m) {
        #pragma unroll
        for (int n = 0; n < 4; ++n) {
            int col = cc0 + n * 16;
            if (col < Nout) {
                #pragma unroll
                for (int j = 0; j < 4; ++j)
                    C[(size_t)(cr0 + m * 16 + j) * Nout + col] = acc[m][n][j];
            }
        }
    }
}

// depthwise causal conv(4) + bias + SiLU, 4 channels/thread
__global__ void conv_silu4(const float* __restrict__ zx, const float* __restrict__ cw,
                           const float* __restrict__ cb, float* __restrict__ xc) {
    int idx = blockIdx.x * blockDim.x + threadIdx.x;
    if (idx >= ROWS * (CONV_DIM / 4)) return;
    int cq = idx % (CONV_DIM / 4);
    int bl = idx / (CONV_DIM / 4);
    int l  = bl % SEQ;
    int c4 = cq * 4;
    const float* base = zx + (size_t)bl * D_IN_PROJ + D_INNER + c4;
    float4 w0 = *(const float4*)(cw + (c4 + 0) * 4);
    float4 w1 = *(const float4*)(cw + (c4 + 1) * 4);
    float4 w2 = *(const float4*)(cw + (c4 + 2) * 4);
    float4 w3 = *(const float4*)(cw + (c4 + 3) * 4);
    float4 zf = make_float4(0.f, 0.f, 0.f, 0.f);
    float4 x3 = (l >= 3) ? *(const float4*)(base - 3 * D_IN_PROJ) : zf;
    float4 x2 = (l >= 2) ? *(const float4*)(base - 2 * D_IN_PROJ) : zf;
    float4 x1 = (l >= 1) ? *(const float4*)(base - 1 * D_IN_PROJ) : zf;
    float4 x0 = *(const float4*)(base);
    float4 bb = *(const float4*)(cb + c4);
    float4 r;
    r.x = siluf(bb.x + w0.x * x3.x + w0.y * x2.x + w0.z * x1.x + w0.w * x0.x);
    r.y = siluf(bb.y + w1.x * x3.y + w1.y * x2.y + w1.z * x1.y + w1.w * x0.y);
    r.z = siluf(bb.z + w2.x * x3.z + w2.y * x2.z + w2.z * x1.z + w2.w * x0.z);
    r.w = siluf(bb.w + w3.x * x3.w + w3.y * x2.w + w3.z * x1.w + w3.w * x0.w);
    *(float4*)(xc + (size_t)bl * CONV_DIM + c4) = r;
}

__global__ void dt_softplus(const float* __restrict__ zx, const float* __restrict__ dtb,
                            float* __restrict__ dtsp) {
    int idx = blockIdx.x * blockDim.x + threadIdx.x;
    if (idx >= ROWS * NHEADS) return;
    int h  = idx & 63;
    int bl = idx >> 6;
    dtsp[idx] = softplusf(zx[(size_t)bl * D_IN_PROJ + (D_INNER + CONV_DIM) + h] + dtb[h]);
}

// per (b, chunk, head) block: 32x32-MFMA intra-chunk Y_diag + end-of-chunk state.
// Wave w owns row-tiles {w, 7-w} (balanced: 9 col-tiles each). P transposed in-register
// via cvt_pkrtz + shfl_xor(32) -- no LDS P roundtrip.
__global__ __launch_bounds__(256, 3) void ssd_chunk(const float* __restrict__ xc,
                                                    const float* __restrict__ dtsp,
                                                    const float* __restrict__ A_log,
                                                    float* __restrict__ ypre,
                                                    float* __restrict__ states,
                                                    float* __restrict__ csb,
                                                    float* __restrict__ csum) {
    __shared__ _Float16 Bb[256][16];
    __shared__ _Float16 Cb[256][16];
    __shared__ _Float16 Xt[16][264];
    __shared__ _Float16 Xdt[16][264];
    __shared__ _Float16 Bt[16][264];
    __shared__ float csL[256];
    __shared__ float wsumL[4];
    __shared__ float stpart[4][16][16];

    const int bid = blockIdx.x;
    const int h = bid & 63;
    const int c = (bid >> 6) & 15;
    const int b = bid >> 10;
    const int t = threadIdx.x;
    const int wv = t >> 6;
    const int lane = t & 63;
    const int fr = lane & 15;
    const int hi = lane >> 4;
    const int l31 = lane & 31;
    const int hi5 = lane >> 5;
    const int row = b * SEQ + c * CHUNK + t;

    // --- cumsum of dA: wave shuffle scan + cross-wave offsets ---
    float Ah  = -__expf(A_log[h]);
    float dtv = dtsp[(size_t)row * NHEADS + h];
    float val = dtv * Ah;
    #pragma unroll
    for (int off = 1; off < 64; off <<= 1) {
        float o = __shfl_up(val, off, 64);
        if (lane >= off) val += o;
    }
    if (lane == 63) wsumL[wv] = val;
    __syncthreads();
    float pre = 0.f, cl = 0.f;
    #pragma unroll
    for (int w2 = 0; w2 < 4; ++w2) {
        float s = wsumL[w2];
        if (w2 < wv) pre += s;
        cl += s;
    }
    float cst = val + pre;
    csL[t] = cst;
    csb[(size_t)bid * 256 + t] = cst;
    if (t == 0) csum[(b * 64 + h) * 16 + c] = cl;
    float dec_t = __expf(cl - cst);

    // --- stage B, C (row-major f16) and X^T, (X*dec)^T, B^T ---
    const float* xrow = xc + (size_t)row * CONV_DIM;
    float bv[16], cv[16], xv[16];
    #pragma unroll
    for (int n = 0; n < 16; n += 4) {
        *(float4*)&bv[n] = *(const float4*)(xrow + D_INNER + n);
        *(float4*)&cv[n] = *(const float4*)(xrow + D_INNER + D_STATE + n);
        *(float4*)&xv[n] = *(const float4*)(xrow + h * HEADDIM + n);
    }
    {
        f16x8 pk;
        #pragma unroll
        for (int n = 0; n < 8; ++n) pk[n] = (_Float16)cv[n];
        *(f16x8*)&Cb[t][0] = pk;
        #pragma unroll
        for (int n = 0; n < 8; ++n) pk[n] = (_Float16)cv[8 + n];
        *(f16x8*)&Cb[t][8] = pk;
        #pragma unroll
        for (int n = 0; n < 8; ++n) pk[n] = (_Float16)bv[n];
        *(f16x8*)&Bb[t][0] = pk;
        #pragma unroll
        for (int n = 0; n < 8; ++n) pk[n] = (_Float16)bv[8 + n];
        *(f16x8*)&Bb[t][8] = pk;
    }
    #pragma unroll
    for (int n = 0; n < 16; ++n) {
        Bt[n][t] = (_Float16)bv[n];
        float xd = xv[n] * dtv;
        Xt[n][t] = (_Float16)xd;
        Xdt[n][t] = (_Float16)(xd * dec_t);
    }
    __syncthreads();

    const int browbase = b * SEQ + c * CHUNK;
    const f32x16 z16 = {};

    // --- Y_diag: wave wv handles row-tiles wv and 7-wv (9 col-tiles total) ---
    #pragma unroll
    for (int halfi = 0; halfi < 2; ++halfi) {
        const int rt = (halfi == 0) ? wv : 7 - wv;
        const int t0 = rt * 32;
        const float cs_t = csL[t0 + l31];
        const f16x8 cfrag = *(const f16x8*)&Cb[t0 + l31][hi5 * 8];
        f32x16 yacc = {};
        for (int sb = 0; sb <= rt; ++sb) {
            const int s0 = sb * 32;
            f16x8 bfrag = *(const f16x8*)&Bb[s0 + l31][hi5 * 8];
            // S'[s][t] = sum_n B[s][n] C[t][n]; lane owns col t=l31, rows s per reg
            f32x16 sp = __builtin_amdgcn_mfma_f32_32x32x16_f16(bfrag, cfrag, z16, 0, 0, 0);
            const bool diag = (sb == rt);
            unsigned int D[8];
            #pragma unroll
            for (int j = 0; j < 8; ++j) {
                const int q0 = 2 * j;
                const int sr0 = (q0 & 3) + 8 * (q0 >> 2) + 4 * hi5;
                float p0 = sp[q0] * __expf(cs_t - csL[s0 + sr0]);
                float p1 = sp[q0 + 1] * __expf(cs_t - csL[s0 + sr0 + 1]);
                if (diag) {
                    p0 = (sr0 <= l31) ? p0 : 0.f;
                    p1 = (sr0 + 1 <= l31) ? p1 : 0.f;
                }
                D[j] = __builtin_bit_cast(unsigned int, __builtin_amdgcn_cvt_pkrtz(p0, p1));
            }
            unsigned int pD[8];
            #pragma unroll
            for (int j = 0; j < 8; ++j) pD[j] = (unsigned int)__shfl_xor((int)D[j], 32, 64);
            // PV k-tile 0 (s_rel 0..15)
            u32x4 fa;
            fa[0] = hi5 ? pD[2] : D[0];
            fa[1] = hi5 ? pD[3] : D[1];
            fa[2] = hi5 ? D[2] : pD[0];
            fa[3] = hi5 ? D[3] : pD[1];
            f16x8 pf0 = __builtin_bit_cast(f16x8, fa);
            f16x8 xf0 = *(const f16x8*)&Xt[fr][s0 + hi5 * 8];
            yacc = __builtin_amdgcn_mfma_f32_32x32x16_f16(pf0, xf0, yacc, 0, 0, 0);
            // PV k-tile 1 (s_rel 16..31)
            fa[0] = hi5 ? pD[6] : D[4];
            fa[1] = hi5 ? pD[7] : D[5];
            fa[2] = hi5 ? D[6] : pD[4];
            fa[3] = hi5 ? D[7] : pD[5];
            f16x8 pf1 = __builtin_bit_cast(f16x8, fa);
            f16x8 xf1 = *(const f16x8*)&Xt[fr][s0 + 16 + hi5 * 8];
            yacc = __builtin_amdgcn_mfma_f32_32x32x16_f16(pf1, xf1, yacc, 0, 0, 0);
        }
        if (l31 < 16) {
            #pragma unroll
            for (int q = 0; q < 16; ++q) {
                const int tr = t0 + (q & 3) + 8 * (q >> 2) + 4 * hi5;
                ypre[(size_t)(browbase + tr) * D_INNER + h * HEADDIM + l31] = yacc[q];
            }
        }
    }

    // --- end-of-chunk state: each wave sums its own 64-s slice ---
    const int r0w = wv * 64;
    f32x4 stacc = {};
    #pragma unroll
    for (int kt = 0; kt < 2; ++kt) {
        f16x8 xa = *(const f16x8*)&Xdt[fr][r0w + kt * 32 + hi * 8];
        f16x8 bb2 = *(const f16x8*)&Bt[fr][r0w + kt * 32 + hi * 8];
        stacc = __builtin_amdgcn_mfma_f32_16x16x32_f16(xa, bb2, stacc, 0, 0, 0);
    }
    #pragma unroll
    for (int j = 0; j < 4; ++j)
        stpart[wv][hi * 4 + j][fr] = stacc[j];
    __syncthreads();
    {
        const int p = t >> 4, n = t & 15;
        float st = stpart[0][p][n] + stpart[1][p][n] + stpart[2][p][n] + stpart[3][p][n];
        states[(size_t)bid * 256 + t] = st;
    }
}

// sequential inter-chunk recurrence (tiny)
__global__ __launch_bounds__(256) void ssd_rec(const float* __restrict__ states,
                                               const float* __restrict__ csum,
                                               float* __restrict__ prevst) {
    const int bh = blockIdx.x;
    const int b = bh >> 6, h = bh & 63;
    const int t = threadIdx.x;
    float run = 0.f;
    for (int c = 0; c < NCHUNK; ++c) {
        size_t idx = ((size_t)((b * 16 + c) * 64 + h)) * 256 + t;
        prevst[idx] = run;
        run = run * expf(csum[bh * 16 + c]) + states[idx];
    }
}

// Fused: Y_off + D skip + SiLU(z) gating + RMSNorm -> bf16 (strided into zx's dead cols)
__global__ __launch_bounds__(512, 4) void ssd_off_norm(const float* __restrict__ xc,
                                                       const float* __restrict__ zx,
                                                       const float* __restrict__ ypre,
                                                       const float* __restrict__ prevst,
                                                       const float* __restrict__ csb,
                                                       const float* __restrict__ Dskip,
                                                       const float* __restrict__ normw,
                                                       unsigned short* __restrict__ yout,
                                                       int ldy) {
    __shared__ float Cs[16][16];
    __shared__ float csS[64][16];
    __shared__ float nw[1024];
    __shared__ float Dn[64];
    __shared__ float red[16][8];

    const int blk = blockIdx.x;
    const int bc = blk >> 4;          // b*16 + c
    const int rb = blk & 15;
    const int r0 = rb * 16;
    const int b = bc >> 4, c = bc & 15;
    const int brow0 = b * SEQ + c * CHUNK;
    const int t = threadIdx.x;
    const int ch0 = t * 2;
    const int h = ch0 >> 4;
    const int p0 = ch0 & 15;
    const int wv = t >> 6;
    const int lane = t & 63;

    if (t < 256) *(float4*)&nw[t * 4] = *(const float4*)(normw + t * 4);
    else if (t < 320) Dn[t - 256] = Dskip[t - 256];
    if (t < 64) {
        int r = t >> 2, n4 = (t & 3) * 4;
        *(float4*)&Cs[r][n4] =
            *(const float4*)(xc + (size_t)(brow0 + r0 + r) * CONV_DIM + D_INNER + D_STATE + n4);
    }
    #pragma unroll
    for (int i = t; i < 1024; i += 512) {
        int r = i & 15, hh = i >> 4;
        csS[hh][r] = csb[(size_t)(bc * 64 + hh) * 256 + r0 + r];
    }

    float ps[2][16];
    {
        const float* pbase = prevst + (size_t)(bc * 64 + h) * 256 + p0 * 16;
        #pragma unroll
        for (int n4 = 0; n4 < 16; n4 += 4) {
            *(float4*)&ps[0][n4] = *(const float4*)(pbase + n4);
            *(float4*)&ps[1][n4] = *(const float4*)(pbase + 16 + n4);
        }
    }
    __syncthreads();

    const float d = Dn[h];
    const float nw0 = nw[ch0], nw1 = nw[ch0 + 1];

    for (int r = 0; r < 16; ++r) {
        const size_t grow = (size_t)(brow0 + r0 + r);
        float2 yv = *(const float2*)(ypre + grow * D_INNER + ch0);
        float2 xv = *(const float2*)(xc + grow * CONV_DIM + ch0);
        float2 zv = *(const float2*)(zx + grow * D_IN_PROJ + ch0);
        float sdo = __expf(csS[h][r]);
        float off0 = 0.f, off1 = 0.f;
        #pragma unroll
        for (int n = 0; n < 16; ++n) {
            float cn = Cs[r][n];
            off0 += cn * ps[0][n];
            off1 += cn * ps[1][n];
        }
        float g0 = (yv.x + sdo * off0 + xv.x * d) * siluf(zv.x);
        float g1 = (yv.y + sdo * off1 + xv.y * d) * siluf(zv.y);
        float s = g0 * g0 + g1 * g1;
        #pragma unroll
        for (int o = 32; o > 0; o >>= 1) s += __shfl_down(s, o, 64);
        if (lane == 0) red[r][wv] = s;
        __syncthreads();
        float tot = 0.f;
        #pragma unroll
        for (int w2 = 0; w2 < 8; ++w2) tot += red[r][w2];
        float rstd = rsqrtf(tot * (1.f / (float)D_INNER) + 1e-5f);
        ushort2 o2;
        o2.x = f2b(g0 * rstd * nw0);
        o2.y = f2b(g1 * rstd * nw1);
        *(ushort2*)(yout + grow * ldy + ch0) = o2;
    }
}

extern "C" void kernel_launch(void* const* d_in, const int* in_sizes, int n_in,
                              void* d_out, int out_size, void* d_ws, size_t ws_size,
                              hipStream_t stream) {
    const float* u     = (const float*)d_in[0];
    const float* Win   = (const float*)d_in[1];
    const float* cw    = (const float*)d_in[2];
    const float* cb    = (const float*)d_in[3];
    const float* dtb   = (const float*)d_in[4];
    const float* Alog  = (const float*)d_in[5];
    const float* Dsk   = (const float*)d_in[6];
    const float* normw = (const float*)d_in[7];
    const float* Wout  = (const float*)d_in[8];
    float* out = (float*)d_out;

    float* ws   = (float*)d_ws;
    float* zx   = ws;                   // 8192*2144 fp32
    float* xc   = zx + 17563648;        // 8192*1056
    float* dtsp = xc + 8650752;         // 524288
    float* csb  = dtsp + 524288;        // 524288
    float* st   = csb + 524288;         // 524288
    float* pst  = st + 524288;          // 524288
    float* csum = pst + 524288;         // 2048
    float* ypre = csum + 2048;          // 8388608
    float* wob  = ypre + 8388608;       // 262144

    unsigned short* u_bf    = (unsigned short*)ypre;
    unsigned short* win_bf  = (unsigned short*)(ypre + 2097152);
    unsigned short* wout_bf = (unsigned short*)wob;
    unsigned short* yn_bf   = (unsigned short*)zx + 2176;

    cast8<<<2048, 256, 0, stream>>>(u, u_bf, 4194304);
    castpad8<<<544, 256, 0, stream>>>(Win, win_bf, 2144 * 512, 2176 * 512);
    cast8<<<256, 256, 0, stream>>>(Wout, wout_bf, 524288);

    gemm_mfma<<<dim3(17, 64), 256, 0, stream>>>(u_bf, win_bf, zx, D_IN_PROJ, D_MODEL, D_MODEL);

    conv_silu4<<<(ROWS * (CONV_DIM / 4)) / 256, 256, 0, stream>>>(zx, cw, cb, xc);
    dt_softplus<<<(ROWS * NHEADS) / 256, 256, 0, stream>>>(zx, dtb, dtsp);
    ssd_chunk<<<BATCH * NCHUNK * NHEADS, 256, 0, stream>>>(xc, dtsp, Alog, ypre, st, csb, csum);
    ssd_rec<<<BATCH * NHEADS, 256, 0, stream>>>(st, csum, pst);
    ssd_off_norm<<<512, 512, 0, stream>>>(xc, zx, ypre, pst, csb, Dsk, normw, yn_bf, 4288);

    gemm_mfma<<<dim3(4, 64), 256, 0, stream>>>(yn_bf, wout_bf, out, D_MODEL, D_INNER, 4288);
}

// Round 6
// 156.417 us; speedup vs baseline: 4.5451x; 1.1955x over previous
//
#include <hip/hip_runtime.h>
#include <hip/hip_bf16.h>
#include <math.h>

#define D_MODEL   512
#define D_INNER   1024
#define NHEADS    64
#define HEADDIM   16
#define D_STATE   16
#define CONV_DIM  1056
#define D_IN_PROJ 2144
#define CHUNK     256
#define NCHUNK    16
#define BATCH     2
#define SEQ       4096
#define ROWS      (BATCH * SEQ)   // 8192
#define LDZX      2176            // padded bf16 row stride of zx

typedef __bf16    bf16x8 __attribute__((ext_vector_type(8)));
typedef _Float16  f16x8  __attribute__((ext_vector_type(8)));
typedef float     f32x4  __attribute__((ext_vector_type(4)));
typedef float     f32x16 __attribute__((ext_vector_type(16)));
typedef unsigned short u16x8 __attribute__((ext_vector_type(8)));
typedef unsigned int   u32x4 __attribute__((ext_vector_type(4)));

__device__ __forceinline__ float softplusf(float x) {
    return (x > 20.f) ? x : log1pf(expf(x));
}
__device__ __forceinline__ float siluf(float x) {
    return x / (1.f + expf(-x));
}
__device__ __forceinline__ unsigned short f2b(float x) {
    union { __hip_bfloat16 h; unsigned short u; } cv;
    cv.h = __float2bfloat16(x);
    return cv.u;
}
__device__ __forceinline__ float b2f(unsigned short u) {
    union { float f; unsigned int i; } c;
    c.i = (unsigned int)u << 16;
    return c.f;
}
__device__ __forceinline__ void load_lds16(const unsigned short* g, unsigned short* l) {
    __builtin_amdgcn_global_load_lds(
        (const __attribute__((address_space(1))) void*)g,
        (__attribute__((address_space(3))) void*)l,
        16, 0, 0);
}

// ---- cast fp32 -> bf16 ----
__global__ __launch_bounds__(256) void cast8(const float* __restrict__ in,
                                             unsigned short* __restrict__ out, int n) {
    int i = (blockIdx.x * blockDim.x + threadIdx.x) * 8;
    if (i >= n) return;
    float4 a = *(const float4*)(in + i);
    float4 b = *(const float4*)(in + i + 4);
    u16x8 o;
    o[0] = f2b(a.x); o[1] = f2b(a.y); o[2] = f2b(a.z); o[3] = f2b(a.w);
    o[4] = f2b(b.x); o[5] = f2b(b.y); o[6] = f2b(b.z); o[7] = f2b(b.w);
    *(u16x8*)(out + i) = o;
}

__global__ __launch_bounds__(256) void castpad8(const float* __restrict__ in,
                                                unsigned short* __restrict__ out,
                                                int n, int npad) {
    int i = (blockIdx.x * blockDim.x + threadIdx.x) * 8;
    if (i >= npad) return;
    u16x8 o;
    if (i + 8 <= n) {
        float4 a = *(const float4*)(in + i);
        float4 b = *(const float4*)(in + i + 4);
        o[0] = f2b(a.x); o[1] = f2b(a.y); o[2] = f2b(a.z); o[3] = f2b(a.w);
        o[4] = f2b(b.x); o[5] = f2b(b.y); o[6] = f2b(b.z); o[7] = f2b(b.w);
    } else {
        #pragma unroll
        for (int j = 0; j < 8; ++j) o[j] = (i + j < n) ? f2b(in[i + j]) : (unsigned short)0;
    }
    *(u16x8*)(out + i) = o;
}

// ---- bf16 MFMA GEMM, double-buffered staging.
// C16 != null: write bf16 to C16 (stride ldc16), plus fp32 dt side-write (cols 2080..2143).
// C16 == null: write fp32 to C32 (stride Nout, col-guarded).
__global__ __launch_bounds__(256) void gemm_mfma(const unsigned short* __restrict__ A,
                                                 const unsigned short* __restrict__ B,
                                                 float* __restrict__ C32,
                                                 unsigned short* __restrict__ C16,
                                                 float* __restrict__ dtout,
                                                 int Nout, int K, int lda, int ldc16) {
    __shared__ unsigned short As[2][128 * 32];
    __shared__ unsigned short Bs[2][128 * 32];
    const int t    = threadIdx.x;
    const int wave = t >> 6;
    const int lane = t & 63;
    const int bm   = blockIdx.y * 128;
    const int bn   = blockIdx.x * 128;
    const int wr   = wave >> 1;
    const int wc   = wave & 1;

    const int srow = wave * 16 + (lane >> 2);
    const int scol = (lane & 3) * 8;
    const unsigned short* ga0 = A + (size_t)(bm + srow) * lda + scol;
    const unsigned short* ga1 = A + (size_t)(bm + 64 + srow) * lda + scol;
    const unsigned short* gb0 = B + (size_t)(bn + srow) * K + scol;
    const unsigned short* gb1 = B + (size_t)(bn + 64 + srow) * K + scol;

    const int fr = lane & 15;
    const int kb = (lane >> 4) * 8;

    f32x4 acc[4][4] = {};
    const int NIT = K >> 5;

    // prologue: stage k-tile 0 into buf 0
    load_lds16(ga0, &As[0][wave * 512]);
    load_lds16(ga1, &As[0][2048 + wave * 512]);
    load_lds16(gb0, &Bs[0][wave * 512]);
    load_lds16(gb1, &Bs[0][2048 + wave * 512]);
    __syncthreads();

    int cur = 0;
    for (int it = 0; it < NIT; ++it) {
        if (it + 1 < NIT) {
            const int k0 = (it + 1) * 32;
            const int nb = cur ^ 1;
            load_lds16(ga0 + k0, &As[nb][wave * 512]);
            load_lds16(ga1 + k0, &As[nb][2048 + wave * 512]);
            load_lds16(gb0 + k0, &Bs[nb][wave * 512]);
            load_lds16(gb1 + k0, &Bs[nb][2048 + wave * 512]);
        }
        const unsigned short* Ab = As[cur];
        const unsigned short* Bb = Bs[cur];
        bf16x8 af[4], bfr[4];
        #pragma unroll
        for (int m = 0; m < 4; ++m)
            af[m] = *reinterpret_cast<const bf16x8*>(&Ab[(wr * 64 + m * 16 + fr) * 32 + kb]);
        #pragma unroll
        for (int n = 0; n < 4; ++n)
            bfr[n] = *reinterpret_cast<const bf16x8*>(&Bb[(wc * 64 + n * 16 + fr) * 32 + kb]);
        #pragma unroll
        for (int m = 0; m < 4; ++m)
            #pragma unroll
            for (int n = 0; n < 4; ++n)
                acc[m][n] = __builtin_amdgcn_mfma_f32_16x16x32_bf16(af[m], bfr[n], acc[m][n], 0, 0, 0);
        __syncthreads();   // drains stage loads (overlapped with compute above) + LDS reads
        cur ^= 1;
    }

    const int cr0 = bm + wr * 64 + ((lane >> 4) << 2);
    const int cc0 = bn + wc * 64 + (lane & 15);
    if (C16) {
        #pragma unroll
        for (int m = 0; m < 4; ++m) {
            #pragma unroll
            for (int n = 0; n < 4; ++n) {
                const int col = cc0 + n * 16;
                #pragma unroll
                for (int j = 0; j < 4; ++j) {
                    const int row = cr0 + m * 16 + j;
                    float v = acc[m][n][j];
                    C16[(size_t)row * ldc16 + col] = f2b(v);
                    if (dtout && col >= 2080 && col < 2144)
                        dtout[(size_t)row * 64 + (col - 2080)] = v;
                }
            }
        }
    } else {
        #pragma unroll
        for (int m = 0; m < 4; ++m) {
            #pragma unroll
            for (int n = 0; n < 4; ++n) {
                const int col = cc0 + n * 16;
                if (col < Nout) {
                    #pragma unroll
                    for (int j = 0; j < 4; ++j)
                        C32[(size_t)(cr0 + m * 16 + j) * Nout + col] = acc[m][n][j];
                }
            }
        }
    }
}

// depthwise causal conv(4) + bias + SiLU, 4 channels/thread, bf16 in/out
__global__ void conv_silu4(const unsigned short* __restrict__ zxb, const float* __restrict__ cw,
                           const float* __restrict__ cb, unsigned short* __restrict__ xcb) {
    int idx = blockIdx.x * blockDim.x + threadIdx.x;
    if (idx >= ROWS * (CONV_DIM / 4)) return;
    int cq = idx % (CONV_DIM / 4);
    int bl = idx / (CONV_DIM / 4);
    int l  = bl % SEQ;
    int c4 = cq * 4;
    const unsigned short* base = zxb + (size_t)bl * LDZX + D_INNER + c4;
    float4 w0 = *(const float4*)(cw + (c4 + 0) * 4);
    float4 w1 = *(const float4*)(cw + (c4 + 1) * 4);
    float4 w2 = *(const float4*)(cw + (c4 + 2) * 4);
    float4 w3 = *(const float4*)(cw + (c4 + 3) * 4);
    float4 zf = make_float4(0.f, 0.f, 0.f, 0.f);
    float4 x3 = zf, x2 = zf, x1 = zf, x0;
    ushort4 u0 = *(const ushort4*)(base);
    x0 = make_float4(b2f(u0.x), b2f(u0.y), b2f(u0.z), b2f(u0.w));
    if (l >= 1) { ushort4 u1 = *(const ushort4*)(base - 1 * LDZX);
                  x1 = make_float4(b2f(u1.x), b2f(u1.y), b2f(u1.z), b2f(u1.w)); }
    if (l >= 2) { ushort4 u2 = *(const ushort4*)(base - 2 * LDZX);
                  x2 = make_float4(b2f(u2.x), b2f(u2.y), b2f(u2.z), b2f(u2.w)); }
    if (l >= 3) { ushort4 u3 = *(const ushort4*)(base - 3 * LDZX);
                  x3 = make_float4(b2f(u3.x), b2f(u3.y), b2f(u3.z), b2f(u3.w)); }
    float4 bb = *(const float4*)(cb + c4);
    ushort4 r;
    r.x = f2b(siluf(bb.x + w0.x * x3.x + w0.y * x2.x + w0.z * x1.x + w0.w * x0.x));
    r.y = f2b(siluf(bb.y + w1.x * x3.y + w1.y * x2.y + w1.z * x1.y + w1.w * x0.y));
    r.z = f2b(siluf(bb.z + w2.x * x3.z + w2.y * x2.z + w2.z * x1.z + w2.w * x0.z));
    r.w = f2b(siluf(bb.w + w3.x * x3.w + w3.y * x2.w + w3.z * x1.w + w3.w * x0.w));
    *(ushort4*)(xcb + (size_t)bl * CONV_DIM + c4) = r;
}

__global__ void dt_softplus(const float* __restrict__ dt_raw, const float* __restrict__ dtb,
                            float* __restrict__ dtsp) {
    int idx = blockIdx.x * blockDim.x + threadIdx.x;
    if (idx >= ROWS * NHEADS) return;
    int h = idx & 63;
    dtsp[idx] = softplusf(dt_raw[idx] + dtb[h]);
}

// per (b, chunk, head) block: 32x32-MFMA intra-chunk Y_diag + end-of-chunk state.
__global__ __launch_bounds__(256, 3) void ssd_chunk(const unsigned short* __restrict__ xcb,
                                                    const float* __restrict__ dtsp,
                                                    const float* __restrict__ A_log,
                                                    float* __restrict__ ypre,
                                                    float* __restrict__ states,
                                                    float* __restrict__ csb,
                                                    float* __restrict__ csum) {
    __shared__ _Float16 Bb[256][16];
    __shared__ _Float16 Cb[256][16];
    __shared__ _Float16 Xt[16][264];
    __shared__ _Float16 Xdt[16][264];
    __shared__ _Float16 Bt[16][264];
    __shared__ float csL[256];
    __shared__ float wsumL[4];
    __shared__ float stpart[4][16][16];

    const int bid = blockIdx.x;
    const int h = bid & 63;
    const int c = (bid >> 6) & 15;
    const int b = bid >> 10;
    const int t = threadIdx.x;
    const int wv = t >> 6;
    const int lane = t & 63;
    const int fr = lane & 15;
    const int hi = lane >> 4;
    const int l31 = lane & 31;
    const int hi5 = lane >> 5;
    const int row = b * SEQ + c * CHUNK + t;

    float Ah  = -__expf(A_log[h]);
    float dtv = dtsp[(size_t)row * NHEADS + h];
    float val = dtv * Ah;
    #pragma unroll
    for (int off = 1; off < 64; off <<= 1) {
        float o = __shfl_up(val, off, 64);
        if (lane >= off) val += o;
    }
    if (lane == 63) wsumL[wv] = val;
    __syncthreads();
    float pre = 0.f, cl = 0.f;
    #pragma unroll
    for (int w2 = 0; w2 < 4; ++w2) {
        float s = wsumL[w2];
        if (w2 < wv) pre += s;
        cl += s;
    }
    float cst = val + pre;
    csL[t] = cst;
    csb[(size_t)bid * 256 + t] = cst;
    if (t == 0) csum[(b * 64 + h) * 16 + c] = cl;
    float dec_t = __expf(cl - cst);

    // --- stage B, C (row-major f16) and X^T, (X*dec)^T, B^T from bf16 xcb ---
    const unsigned short* xrow = xcb + (size_t)row * CONV_DIM;
    u16x8 braw0 = *(const u16x8*)(xrow + D_INNER);
    u16x8 braw1 = *(const u16x8*)(xrow + D_INNER + 8);
    u16x8 craw0 = *(const u16x8*)(xrow + D_INNER + D_STATE);
    u16x8 craw1 = *(const u16x8*)(xrow + D_INNER + D_STATE + 8);
    u16x8 xraw0 = *(const u16x8*)(xrow + h * HEADDIM);
    u16x8 xraw1 = *(const u16x8*)(xrow + h * HEADDIM + 8);
    float bv[16], cv[16], xv[16];
    #pragma unroll
    for (int n = 0; n < 8; ++n) {
        bv[n] = b2f(braw0[n]); bv[8 + n] = b2f(braw1[n]);
        cv[n] = b2f(craw0[n]); cv[8 + n] = b2f(craw1[n]);
        xv[n] = b2f(xraw0[n]); xv[8 + n] = b2f(xraw1[n]);
    }
    {
        f16x8 pk;
        #pragma unroll
        for (int n = 0; n < 8; ++n) pk[n] = (_Float16)cv[n];
        *(f16x8*)&Cb[t][0] = pk;
        #pragma unroll
        for (int n = 0; n < 8; ++n) pk[n] = (_Float16)cv[8 + n];
        *(f16x8*)&Cb[t][8] = pk;
        #pragma unroll
        for (int n = 0; n < 8; ++n) pk[n] = (_Float16)bv[n];
        *(f16x8*)&Bb[t][0] = pk;
        #pragma unroll
        for (int n = 0; n < 8; ++n) pk[n] = (_Float16)bv[8 + n];
        *(f16x8*)&Bb[t][8] = pk;
    }
    #pragma unroll
    for (int n = 0; n < 16; ++n) {
        Bt[n][t] = (_Float16)bv[n];
        float xd = xv[n] * dtv;
        Xt[n][t] = (_Float16)xd;
        Xdt[n][t] = (_Float16)(xd * dec_t);
    }
    __syncthreads();

    const int browbase = b * SEQ + c * CHUNK;
    const f32x16 z16 = {};

    #pragma unroll
    for (int halfi = 0; halfi < 2; ++halfi) {
        const int rt = (halfi == 0) ? wv : 7 - wv;
        const int t0 = rt * 32;
        const float cs_t = csL[t0 + l31];
        const f16x8 cfrag = *(const f16x8*)&Cb[t0 + l31][hi5 * 8];
        f32x16 yacc = {};
        for (int sb = 0; sb <= rt; ++sb) {
            const int s0 = sb * 32;
            f16x8 bfrag = *(const f16x8*)&Bb[s0 + l31][hi5 * 8];
            f32x16 sp = __builtin_amdgcn_mfma_f32_32x32x16_f16(bfrag, cfrag, z16, 0, 0, 0);
            const bool diag = (sb == rt);
            unsigned int D[8];
            #pragma unroll
            for (int j = 0; j < 8; ++j) {
                const int q0 = 2 * j;
                const int sr0 = (q0 & 3) + 8 * (q0 >> 2) + 4 * hi5;
                float p0 = sp[q0] * __expf(cs_t - csL[s0 + sr0]);
                float p1 = sp[q0 + 1] * __expf(cs_t - csL[s0 + sr0 + 1]);
                if (diag) {
                    p0 = (sr0 <= l31) ? p0 : 0.f;
                    p1 = (sr0 + 1 <= l31) ? p1 : 0.f;
                }
                D[j] = __builtin_bit_cast(unsigned int, __builtin_amdgcn_cvt_pkrtz(p0, p1));
            }
            unsigned int pD[8];
            #pragma unroll
            for (int j = 0; j < 8; ++j) pD[j] = (unsigned int)__shfl_xor((int)D[j], 32, 64);
            u32x4 fa;
            fa[0] = hi5 ? pD[2] : D[0];
            fa[1] = hi5 ? pD[3] : D[1];
            fa[2] = hi5 ? D[2] : pD[0];
            fa[3] = hi5 ? D[3] : pD[1];
            f16x8 pf0 = __builtin_bit_cast(f16x8, fa);
            f16x8 xf0 = *(const f16x8*)&Xt[fr][s0 + hi5 * 8];
            yacc = __builtin_amdgcn_mfma_f32_32x32x16_f16(pf0, xf0, yacc, 0, 0, 0);
            fa[0] = hi5 ? pD[6] : D[4];
            fa[1] = hi5 ? pD[7] : D[5];
            fa[2] = hi5 ? D[6] : pD[4];
            fa[3] = hi5 ? D[7] : pD[5];
            f16x8 pf1 = __builtin_bit_cast(f16x8, fa);
            f16x8 xf1 = *(const f16x8*)&Xt[fr][s0 + 16 + hi5 * 8];
            yacc = __builtin_amdgcn_mfma_f32_32x32x16_f16(pf1, xf1, yacc, 0, 0, 0);
        }
        if (l31 < 16) {
            #pragma unroll
            for (int q = 0; q < 16; ++q) {
                const int tr = t0 + (q & 3) + 8 * (q >> 2) + 4 * hi5;
                ypre[(size_t)(browbase + tr) * D_INNER + h * HEADDIM + l31] = yacc[q];
            }
        }
    }

    const int r0w = wv * 64;
    f32x4 stacc = {};
    #pragma unroll
    for (int kt = 0; kt < 2; ++kt) {
        f16x8 xa = *(const f16x8*)&Xdt[fr][r0w + kt * 32 + hi * 8];
        f16x8 bb2 = *(const f16x8*)&Bt[fr][r0w + kt * 32 + hi * 8];
        stacc = __builtin_amdgcn_mfma_f32_16x16x32_f16(xa, bb2, stacc, 0, 0, 0);
    }
    #pragma unroll
    for (int j = 0; j < 4; ++j)
        stpart[wv][hi * 4 + j][fr] = stacc[j];
    __syncthreads();
    {
        const int p = t >> 4, n = t & 15;
        float st = stpart[0][p][n] + stpart[1][p][n] + stpart[2][p][n] + stpart[3][p][n];
        states[(size_t)bid * 256 + t] = st;
    }
}

// sequential inter-chunk recurrence (tiny)
__global__ __launch_bounds__(256) void ssd_rec(const float* __restrict__ states,
                                               const float* __restrict__ csum,
                                               float* __restrict__ prevst) {
    const int bh = blockIdx.x;
    const int b = bh >> 6, h = bh & 63;
    const int t = threadIdx.x;
    float run = 0.f;
    for (int c = 0; c < NCHUNK; ++c) {
        size_t idx = ((size_t)((b * 16 + c) * 64 + h)) * 256 + t;
        prevst[idx] = run;
        run = run * expf(csum[bh * 16 + c]) + states[idx];
    }
}

// Fused: Y_off + D skip + SiLU(z) gating + RMSNorm -> bf16
__global__ __launch_bounds__(512, 4) void ssd_off_norm(const unsigned short* __restrict__ xcb,
                                                       const unsigned short* __restrict__ zxb,
                                                       const float* __restrict__ ypre,
                                                       const float* __restrict__ prevst,
                                                       const float* __restrict__ csb,
                                                       const float* __restrict__ Dskip,
                                                       const float* __restrict__ normw,
                                                       unsigned short* __restrict__ yout) {
    __shared__ float Cs[16][16];
    __shared__ float csS[64][16];
    __shared__ float nw[1024];
    __shared__ float Dn[64];
    __shared__ float red[16][8];

    const int blk = blockIdx.x;
    const int bc = blk >> 4;          // b*16 + c
    const int rb = blk & 15;
    const int r0 = rb * 16;
    const int b = bc >> 4, c = bc & 15;
    const int brow0 = b * SEQ + c * CHUNK;
    const int t = threadIdx.x;
    const int ch0 = t * 2;
    const int h = ch0 >> 4;
    const int p0 = ch0 & 15;
    const int wv = t >> 6;
    const int lane = t & 63;

    if (t < 256) *(float4*)&nw[t * 4] = *(const float4*)(normw + t * 4);
    else if (t < 320) Dn[t - 256] = Dskip[t - 256];
    if (t < 64) {
        int r = t >> 2, n4 = (t & 3) * 4;
        ushort4 uu = *(const ushort4*)(xcb + (size_t)(brow0 + r0 + r) * CONV_DIM
                                       + D_INNER + D_STATE + n4);
        Cs[r][n4 + 0] = b2f(uu.x); Cs[r][n4 + 1] = b2f(uu.y);
        Cs[r][n4 + 2] = b2f(uu.z); Cs[r][n4 + 3] = b2f(uu.w);
    }
    #pragma unroll
    for (int i = t; i < 1024; i += 512) {
        int r = i & 15, hh = i >> 4;
        csS[hh][r] = csb[(size_t)(bc * 64 + hh) * 256 + r0 + r];
    }

    float ps[2][16];
    {
        const float* pbase = prevst + (size_t)(bc * 64 + h) * 256 + p0 * 16;
        #pragma unroll
        for (int n4 = 0; n4 < 16; n4 += 4) {
            *(float4*)&ps[0][n4] = *(const float4*)(pbase + n4);
            *(float4*)&ps[1][n4] = *(const float4*)(pbase + 16 + n4);
        }
    }
    __syncthreads();

    const float d = Dn[h];
    const float nw0 = nw[ch0], nw1 = nw[ch0 + 1];

    for (int r = 0; r < 16; ++r) {
        const size_t grow = (size_t)(brow0 + r0 + r);
        float2 yv = *(const float2*)(ypre + grow * D_INNER + ch0);
        ushort2 xu = *(const ushort2*)(xcb + grow * CONV_DIM + ch0);
        ushort2 zu = *(const ushort2*)(zxb + grow * LDZX + ch0);
        float sdo = __expf(csS[h][r]);
        float off0 = 0.f, off1 = 0.f;
        #pragma unroll
        for (int n = 0; n < 16; ++n) {
            float cn = Cs[r][n];
            off0 += cn * ps[0][n];
            off1 += cn * ps[1][n];
        }
        float g0 = (yv.x + sdo * off0 + b2f(xu.x) * d) * siluf(b2f(zu.x));
        float g1 = (yv.y + sdo * off1 + b2f(xu.y) * d) * siluf(b2f(zu.y));
        float s = g0 * g0 + g1 * g1;
        #pragma unroll
        for (int o = 32; o > 0; o >>= 1) s += __shfl_down(s, o, 64);
        if (lane == 0) red[r][wv] = s;
        __syncthreads();
        float tot = 0.f;
        #pragma unroll
        for (int w2 = 0; w2 < 8; ++w2) tot += red[r][w2];
        float rstd = rsqrtf(tot * (1.f / (float)D_INNER) + 1e-5f);
        ushort2 o2;
        o2.x = f2b(g0 * rstd * nw0);
        o2.y = f2b(g1 * rstd * nw1);
        *(ushort2*)(yout + grow * D_INNER + ch0) = o2;
    }
}

extern "C" void kernel_launch(void* const* d_in, const int* in_sizes, int n_in,
                              void* d_out, int out_size, void* d_ws, size_t ws_size,
                              hipStream_t stream) {
    const float* u     = (const float*)d_in[0];
    const float* Win   = (const float*)d_in[1];
    const float* cw    = (const float*)d_in[2];
    const float* cb    = (const float*)d_in[3];
    const float* dtb   = (const float*)d_in[4];
    const float* Alog  = (const float*)d_in[5];
    const float* Dsk   = (const float*)d_in[6];
    const float* normw = (const float*)d_in[7];
    const float* Wout  = (const float*)d_in[8];
    float* out = (float*)d_out;

    float* ws = (float*)d_ws;
    unsigned short* zxb = (unsigned short*)ws;          // 8192*2176 bf16 = 8,912,896 f32
    float* dt_raw = ws + 8912896;                       // 524288
    float* dtsp   = dt_raw + 524288;                    // 524288
    float* csb    = dtsp + 524288;                      // 524288
    float* st     = csb + 524288;                       // 524288
    float* pst    = st + 524288;                        // 524288
    float* csum   = pst + 524288;                       // 2048
    float* ypre   = csum + 2048;                        // 8388608
    unsigned short* xcb   = (unsigned short*)(ypre + 8388608);          // 8,650,752 bf16
    unsigned short* yn_bf = (unsigned short*)((float*)xcb + 4325376);   // 8192*1024 bf16
    unsigned short* u_bf  = (unsigned short*)((float*)yn_bf + 2097152); // 8192*512 bf16
    unsigned short* win_bf  = (unsigned short*)((float*)u_bf + 2097152);  // 2176*512 bf16
    unsigned short* wout_bf = (unsigned short*)((float*)win_bf + 557056); // 512*1024 bf16

    cast8<<<2048, 256, 0, stream>>>(u, u_bf, 4194304);
    castpad8<<<544, 256, 0, stream>>>(Win, win_bf, 2144 * 512, 2176 * 512);
    cast8<<<256, 256, 0, stream>>>(Wout, wout_bf, 524288);

    // in_proj: bf16 C (stride 2176) + fp32 dt side-write
    gemm_mfma<<<dim3(17, 64), 256, 0, stream>>>(u_bf, win_bf, nullptr, zxb, dt_raw,
                                                D_IN_PROJ, D_MODEL, D_MODEL, LDZX);

    conv_silu4<<<(ROWS * (CONV_DIM / 4)) / 256, 256, 0, stream>>>(zxb, cw, cb, xcb);
    dt_softplus<<<(ROWS * NHEADS) / 256, 256, 0, stream>>>(dt_raw, dtb, dtsp);
    ssd_chunk<<<BATCH * NCHUNK * NHEADS, 256, 0, stream>>>(xcb, dtsp, Alog, ypre, st, csb, csum);
    ssd_rec<<<BATCH * NHEADS, 256, 0, stream>>>(st, csum, pst);
    ssd_off_norm<<<512, 512, 0, stream>>>(xcb, zxb, ypre, pst, csb, Dsk, normw, yn_bf);

    // out_proj: fp32 C
    gemm_mfma<<<dim3(4, 64), 256, 0, stream>>>(yn_bf, wout_bf, out, nullptr, nullptr,
                                               D_MODEL, D_INNER, D_INNER, 0);
}

// Round 7
// 149.461 us; speedup vs baseline: 4.7566x; 1.0465x over previous
//
#include <hip/hip_runtime.h>
#include <hip/hip_bf16.h>
#include <math.h>

#define D_MODEL   512
#define D_INNER   1024
#define NHEADS    64
#define HEADDIM   16
#define D_STATE   16
#define CONV_DIM  1056
#define D_IN_PROJ 2144
#define CHUNK     256
#define NCHUNK    16
#define BATCH     2
#define SEQ       4096
#define ROWS      (BATCH * SEQ)   // 8192
#define LDZX      2176            // padded bf16 row stride of zx

typedef __bf16    bf16x8 __attribute__((ext_vector_type(8)));
typedef _Float16  f16x8  __attribute__((ext_vector_type(8)));
typedef float     f32x4  __attribute__((ext_vector_type(4)));
typedef float     f32x16 __attribute__((ext_vector_type(16)));
typedef unsigned short u16x8 __attribute__((ext_vector_type(8)));
typedef unsigned int   u32x4 __attribute__((ext_vector_type(4)));

__device__ __forceinline__ float softplusf(float x) {
    return (x > 20.f) ? x : log1pf(expf(x));
}
__device__ __forceinline__ float siluf(float x) {
    return x / (1.f + expf(-x));
}
__device__ __forceinline__ unsigned short f2b(float x) {
    union { __hip_bfloat16 h; unsigned short u; } cv;
    cv.h = __float2bfloat16(x);
    return cv.u;
}
__device__ __forceinline__ float b2f(unsigned short u) {
    union { float f; unsigned int i; } c;
    c.i = (unsigned int)u << 16;
    return c.f;
}
__device__ __forceinline__ void load_lds16(const unsigned short* g, unsigned short* l) {
    __builtin_amdgcn_global_load_lds(
        (const __attribute__((address_space(1))) void*)g,
        (__attribute__((address_space(3))) void*)l,
        16, 0, 0);
}

// ---- cast fp32 -> bf16 ----
__global__ __launch_bounds__(256) void cast8(const float* __restrict__ in,
                                             unsigned short* __restrict__ out, int n) {
    int i = (blockIdx.x * blockDim.x + threadIdx.x) * 8;
    if (i >= n) return;
    float4 a = *(const float4*)(in + i);
    float4 b = *(const float4*)(in + i + 4);
    u16x8 o;
    o[0] = f2b(a.x); o[1] = f2b(a.y); o[2] = f2b(a.z); o[3] = f2b(a.w);
    o[4] = f2b(b.x); o[5] = f2b(b.y); o[6] = f2b(b.z); o[7] = f2b(b.w);
    *(u16x8*)(out + i) = o;
}

__global__ __launch_bounds__(256) void castpad8(const float* __restrict__ in,
                                                unsigned short* __restrict__ out,
                                                int n, int npad) {
    int i = (blockIdx.x * blockDim.x + threadIdx.x) * 8;
    if (i >= npad) return;
    u16x8 o;
    if (i + 8 <= n) {
        float4 a = *(const float4*)(in + i);
        float4 b = *(const float4*)(in + i + 4);
        o[0] = f2b(a.x); o[1] = f2b(a.y); o[2] = f2b(a.z); o[3] = f2b(a.w);
        o[4] = f2b(b.x); o[5] = f2b(b.y); o[6] = f2b(b.z); o[7] = f2b(b.w);
    } else {
        #pragma unroll
        for (int j = 0; j < 8; ++j) o[j] = (i + j < n) ? f2b(in[i + j]) : (unsigned short)0;
    }
    *(u16x8*)(out + i) = o;
}

// ---- bf16 MFMA GEMM, double-buffered staging, XCD-swizzled 1-D grid.
// C16 != null: LDS-transposed bf16 epilogue (stride ldc16) + fused softplus(dt) side-write.
// C16 == null: fp32 C32 (stride 512).
__global__ __launch_bounds__(256) void gemm_mfma(const unsigned short* __restrict__ A,
                                                 const unsigned short* __restrict__ B,
                                                 float* __restrict__ C32,
                                                 unsigned short* __restrict__ C16,
                                                 float* __restrict__ dtsp,
                                                 const float* __restrict__ dtb,
                                                 int K, int lda, int ldc16, int nbx) {
    __shared__ unsigned short smem[16384];   // 2x A-buf (0,4096) + 2x B-buf (8192,12288); epilogue CT[128][128]
    const int t    = threadIdx.x;
    const int wave = t >> 6;
    const int lane = t & 63;
    // bijective XCD swizzle (grid % 8 == 0)
    const int cpx = gridDim.x >> 3;
    const int bid = blockIdx.x;
    const int swz = (bid & 7) * cpx + (bid >> 3);
    const int by = swz / nbx;
    const int bx = swz - by * nbx;
    const int bm = by * 128;
    const int bn = bx * 128;
    const int wr = wave >> 1;
    const int wc = wave & 1;

    const int srow = wave * 16 + (lane >> 2);
    const int scol = (lane & 3) * 8;
    const unsigned short* ga0 = A + (size_t)(bm + srow) * lda + scol;
    const unsigned short* ga1 = A + (size_t)(bm + 64 + srow) * lda + scol;
    const unsigned short* gb0 = B + (size_t)(bn + srow) * K + scol;
    const unsigned short* gb1 = B + (size_t)(bn + 64 + srow) * K + scol;

    const int fr = lane & 15;
    const int kb = (lane >> 4) * 8;

    f32x4 acc[4][4] = {};
    const int NIT = K >> 5;

    load_lds16(ga0, smem + wave * 512);
    load_lds16(ga1, smem + 2048 + wave * 512);
    load_lds16(gb0, smem + 8192 + wave * 512);
    load_lds16(gb1, smem + 8192 + 2048 + wave * 512);
    __syncthreads();

    int cur = 0;
    for (int it = 0; it < NIT; ++it) {
        if (it + 1 < NIT) {
            const int k0 = (it + 1) * 32;
            const int nb = cur ^ 1;
            load_lds16(ga0 + k0, smem + nb * 4096 + wave * 512);
            load_lds16(ga1 + k0, smem + nb * 4096 + 2048 + wave * 512);
            load_lds16(gb0 + k0, smem + 8192 + nb * 4096 + wave * 512);
            load_lds16(gb1 + k0, smem + 8192 + nb * 4096 + 2048 + wave * 512);
        }
        const unsigned short* Ab = smem + cur * 4096;
        const unsigned short* Bb = smem + 8192 + cur * 4096;
        bf16x8 af[4], bfr[4];
        #pragma unroll
        for (int m = 0; m < 4; ++m)
            af[m] = *reinterpret_cast<const bf16x8*>(&Ab[(wr * 64 + m * 16 + fr) * 32 + kb]);
        #pragma unroll
        for (int n = 0; n < 4; ++n)
            bfr[n] = *reinterpret_cast<const bf16x8*>(&Bb[(wc * 64 + n * 16 + fr) * 32 + kb]);
        #pragma unroll
        for (int m = 0; m < 4; ++m)
            #pragma unroll
            for (int n = 0; n < 4; ++n)
                acc[m][n] = __builtin_amdgcn_mfma_f32_16x16x32_bf16(af[m], bfr[n], acc[m][n], 0, 0, 0);
        __syncthreads();
        cur ^= 1;
    }

    if (C16) {
        // fused dt softplus side-write (only the bn==2048 block column hits the range)
        if (dtsp && bn == 2048) {
            #pragma unroll
            for (int m = 0; m < 4; ++m) {
                #pragma unroll
                for (int n = 0; n < 4; ++n) {
                    const int col = bn + wc * 64 + fr + n * 16;
                    if (col >= 2080 && col < 2144) {
                        const int h = col - 2080;
                        const float bias = dtb[h];
                        #pragma unroll
                        for (int j = 0; j < 4; ++j) {
                            const int row = bm + wr * 64 + ((lane >> 4) << 2) + m * 16 + j;
                            dtsp[(size_t)row * 64 + h] = softplusf(acc[m][n][j] + bias);
                        }
                    }
                }
            }
        }
        // LDS transpose -> coalesced u16x8 stores
        #pragma unroll
        for (int m = 0; m < 4; ++m) {
            #pragma unroll
            for (int n = 0; n < 4; ++n) {
                const int lcol = wc * 64 + fr + n * 16;
                #pragma unroll
                for (int j = 0; j < 4; ++j) {
                    const int lrow = wr * 64 + ((lane >> 4) << 2) + m * 16 + j;
                    smem[lrow * 128 + lcol] = f2b(acc[m][n][j]);
                }
            }
        }
        __syncthreads();
        #pragma unroll
        for (int p = 0; p < 8; ++p) {
            const int r = p * 16 + (t >> 4);
            const int cl = (t & 15) * 8;
            u16x8 v = *(const u16x8*)&smem[r * 128 + cl];
            *(u16x8*)(C16 + (size_t)(bm + r) * ldc16 + bn + cl) = v;
        }
    } else {
        const int cr0 = bm + wr * 64 + ((lane >> 4) << 2);
        const int cc0 = bn + wc * 64 + fr;
        #pragma unroll
        for (int m = 0; m < 4; ++m)
            #pragma unroll
            for (int n = 0; n < 4; ++n)
                #pragma unroll
                for (int j = 0; j < 4; ++j)
                    C32[(size_t)(cr0 + m * 16 + j) * 512 + cc0 + n * 16] = acc[m][n][j];
    }
}

// depthwise causal conv(4) + bias + SiLU; 4 rows x 4 channels per thread
__global__ void conv_silu44(const unsigned short* __restrict__ zxb, const float* __restrict__ cw,
                            const float* __restrict__ cb, unsigned short* __restrict__ xcb) {
    int idx = blockIdx.x * blockDim.x + threadIdx.x;
    if (idx >= (ROWS / 4) * (CONV_DIM / 4)) return;
    const int cq  = idx % (CONV_DIM / 4);
    const int blq = idx / (CONV_DIM / 4);
    const int bl0 = blq * 4;
    const int l0  = bl0 % SEQ;
    const int c4  = cq * 4;
    const unsigned short* base = zxb + (size_t)bl0 * LDZX + D_INNER + c4;
    float4 w0 = *(const float4*)(cw + (c4 + 0) * 4);
    float4 w1 = *(const float4*)(cw + (c4 + 1) * 4);
    float4 w2 = *(const float4*)(cw + (c4 + 2) * 4);
    float4 w3 = *(const float4*)(cw + (c4 + 3) * 4);
    float4 bb = *(const float4*)(cb + c4);
    float4 in[7];
    #pragma unroll
    for (int k = 0; k < 7; ++k) {
        const int off = k - 3;   // row bl0+off
        if (l0 == 0 && k < 3) {
            in[k] = make_float4(0.f, 0.f, 0.f, 0.f);
        } else {
            ushort4 uu = *(const ushort4*)(base + (long)off * LDZX);
            in[k] = make_float4(b2f(uu.x), b2f(uu.y), b2f(uu.z), b2f(uu.w));
        }
    }
    #pragma unroll
    for (int r = 0; r < 4; ++r) {
        ushort4 o;
        o.x = f2b(siluf(bb.x + w0.x * in[r].x + w0.y * in[r + 1].x + w0.z * in[r + 2].x + w0.w * in[r + 3].x));
        o.y = f2b(siluf(bb.y + w1.x * in[r].y + w1.y * in[r + 1].y + w1.z * in[r + 2].y + w1.w * in[r + 3].y));
        o.z = f2b(siluf(bb.z + w2.x * in[r].z + w2.y * in[r + 1].z + w2.z * in[r + 2].z + w2.w * in[r + 3].z));
        o.w = f2b(siluf(bb.w + w3.x * in[r].w + w3.y * in[r + 1].w + w3.z * in[r + 2].w + w3.w * in[r + 3].w));
        *(ushort4*)(xcb + (size_t)(bl0 + r) * CONV_DIM + c4) = o;
    }
}

// per (b, chunk, head) block: 32x32-MFMA intra-chunk Y_diag + end-of-chunk state.
__global__ __launch_bounds__(256, 3) void ssd_chunk(const unsigned short* __restrict__ xcb,
                                                    const float* __restrict__ dtsp,
                                                    const float* __restrict__ A_log,
                                                    unsigned short* __restrict__ ypre16,
                                                    float* __restrict__ states,
                                                    float* __restrict__ csb,
                                                    float* __restrict__ csum) {
    __shared__ _Float16 Bb[256][16];
    __shared__ _Float16 Cb[256][16];
    __shared__ _Float16 Xt[16][264];
    __shared__ _Float16 Xdt[16][264];
    __shared__ _Float16 Bt[16][264];
    __shared__ float csL[256];
    __shared__ float wsumL[4];
    __shared__ float stpart[4][16][16];

    const int bid = blockIdx.x;
    const int h = bid & 63;
    const int c = (bid >> 6) & 15;
    const int b = bid >> 10;
    const int t = threadIdx.x;
    const int wv = t >> 6;
    const int lane = t & 63;
    const int fr = lane & 15;
    const int hi = lane >> 4;
    const int l31 = lane & 31;
    const int hi5 = lane >> 5;
    const int row = b * SEQ + c * CHUNK + t;

    float Ah  = -__expf(A_log[h]);
    float dtv = dtsp[(size_t)row * NHEADS + h];
    float val = dtv * Ah;
    #pragma unroll
    for (int off = 1; off < 64; off <<= 1) {
        float o = __shfl_up(val, off, 64);
        if (lane >= off) val += o;
    }
    if (lane == 63) wsumL[wv] = val;
    __syncthreads();
    float pre = 0.f, cl = 0.f;
    #pragma unroll
    for (int w2 = 0; w2 < 4; ++w2) {
        float s = wsumL[w2];
        if (w2 < wv) pre += s;
        cl += s;
    }
    float cst = val + pre;
    csL[t] = cst;
    csb[(size_t)bid * 256 + t] = cst;
    if (t == 0) csum[(b * 64 + h) * 16 + c] = cl;
    float dec_t = __expf(cl - cst);

    const unsigned short* xrow = xcb + (size_t)row * CONV_DIM;
    u16x8 braw0 = *(const u16x8*)(xrow + D_INNER);
    u16x8 braw1 = *(const u16x8*)(xrow + D_INNER + 8);
    u16x8 craw0 = *(const u16x8*)(xrow + D_INNER + D_STATE);
    u16x8 craw1 = *(const u16x8*)(xrow + D_INNER + D_STATE + 8);
    u16x8 xraw0 = *(const u16x8*)(xrow + h * HEADDIM);
    u16x8 xraw1 = *(const u16x8*)(xrow + h * HEADDIM + 8);
    float bv[16], cv[16], xv[16];
    #pragma unroll
    for (int n = 0; n < 8; ++n) {
        bv[n] = b2f(braw0[n]); bv[8 + n] = b2f(braw1[n]);
        cv[n] = b2f(craw0[n]); cv[8 + n] = b2f(craw1[n]);
        xv[n] = b2f(xraw0[n]); xv[8 + n] = b2f(xraw1[n]);
    }
    {
        f16x8 pk;
        #pragma unroll
        for (int n = 0; n < 8; ++n) pk[n] = (_Float16)cv[n];
        *(f16x8*)&Cb[t][0] = pk;
        #pragma unroll
        for (int n = 0; n < 8; ++n) pk[n] = (_Float16)cv[8 + n];
        *(f16x8*)&Cb[t][8] = pk;
        #pragma unroll
        for (int n = 0; n < 8; ++n) pk[n] = (_Float16)bv[n];
        *(f16x8*)&Bb[t][0] = pk;
        #pragma unroll
        for (int n = 0; n < 8; ++n) pk[n] = (_Float16)bv[8 + n];
        *(f16x8*)&Bb[t][8] = pk;
    }
    #pragma unroll
    for (int n = 0; n < 16; ++n) {
        Bt[n][t] = (_Float16)bv[n];
        float xd = xv[n] * dtv;
        Xt[n][t] = (_Float16)xd;
        Xdt[n][t] = (_Float16)(xd * dec_t);
    }
    __syncthreads();

    const int browbase = b * SEQ + c * CHUNK;
    const f32x16 z16 = {};

    #pragma unroll
    for (int halfi = 0; halfi < 2; ++halfi) {
        const int rt = (halfi == 0) ? wv : 7 - wv;
        const int t0 = rt * 32;
        const float cs_t = csL[t0 + l31];
        const f16x8 cfrag = *(const f16x8*)&Cb[t0 + l31][hi5 * 8];
        f32x16 yacc = {};
        for (int sb = 0; sb <= rt; ++sb) {
            const int s0 = sb * 32;
            f16x8 bfrag = *(const f16x8*)&Bb[s0 + l31][hi5 * 8];
            f32x16 sp = __builtin_amdgcn_mfma_f32_32x32x16_f16(bfrag, cfrag, z16, 0, 0, 0);
            const bool diag = (sb == rt);
            unsigned int D[8];
            #pragma unroll
            for (int j = 0; j < 8; ++j) {
                const int q0 = 2 * j;
                const int sr0 = (q0 & 3) + 8 * (q0 >> 2) + 4 * hi5;
                float p0 = sp[q0] * __expf(cs_t - csL[s0 + sr0]);
                float p1 = sp[q0 + 1] * __expf(cs_t - csL[s0 + sr0 + 1]);
                if (diag) {
                    p0 = (sr0 <= l31) ? p0 : 0.f;
                    p1 = (sr0 + 1 <= l31) ? p1 : 0.f;
                }
                D[j] = __builtin_bit_cast(unsigned int, __builtin_amdgcn_cvt_pkrtz(p0, p1));
            }
            unsigned int pD[8];
            #pragma unroll
            for (int j = 0; j < 8; ++j) pD[j] = (unsigned int)__shfl_xor((int)D[j], 32, 64);
            u32x4 fa;
            fa[0] = hi5 ? pD[2] : D[0];
            fa[1] = hi5 ? pD[3] : D[1];
            fa[2] = hi5 ? D[2] : pD[0];
            fa[3] = hi5 ? D[3] : pD[1];
            f16x8 pf0 = __builtin_bit_cast(f16x8, fa);
            f16x8 xf0 = *(const f16x8*)&Xt[fr][s0 + hi5 * 8];
            yacc = __builtin_amdgcn_mfma_f32_32x32x16_f16(pf0, xf0, yacc, 0, 0, 0);
            fa[0] = hi5 ? pD[6] : D[4];
            fa[1] = hi5 ? pD[7] : D[5];
            fa[2] = hi5 ? D[6] : pD[4];
            fa[3] = hi5 ? D[7] : pD[5];
            f16x8 pf1 = __builtin_bit_cast(f16x8, fa);
            f16x8 xf1 = *(const f16x8*)&Xt[fr][s0 + 16 + hi5 * 8];
            yacc = __builtin_amdgcn_mfma_f32_32x32x16_f16(pf1, xf1, yacc, 0, 0, 0);
        }
        if (l31 < 16) {
            #pragma unroll
            for (int q = 0; q < 16; ++q) {
                const int tr = t0 + (q & 3) + 8 * (q >> 2) + 4 * hi5;
                ypre16[(size_t)(browbase + tr) * D_INNER + h * HEADDIM + l31] = f2b(yacc[q]);
            }
        }
    }

    const int r0w = wv * 64;
    f32x4 stacc = {};
    #pragma unroll
    for (int kt = 0; kt < 2; ++kt) {
        f16x8 xa = *(const f16x8*)&Xdt[fr][r0w + kt * 32 + hi * 8];
        f16x8 bb2 = *(const f16x8*)&Bt[fr][r0w + kt * 32 + hi * 8];
        stacc = __builtin_amdgcn_mfma_f32_16x16x32_f16(xa, bb2, stacc, 0, 0, 0);
    }
    #pragma unroll
    for (int j = 0; j < 4; ++j)
        stpart[wv][hi * 4 + j][fr] = stacc[j];
    __syncthreads();
    {
        const int p = t >> 4, n = t & 15;
        float st = stpart[0][p][n] + stpart[1][p][n] + stpart[2][p][n] + stpart[3][p][n];
        states[(size_t)bid * 256 + t] = st;
    }
}

// inter-chunk recurrence: prefetch all chunk states, then serial combine in-register
__global__ __launch_bounds__(256) void ssd_rec(const float* __restrict__ states,
                                               const float* __restrict__ csum,
                                               float* __restrict__ prevst) {
    __shared__ float dec[16];
    const int bh = blockIdx.x;
    const int b = bh >> 6, h = bh & 63;
    const int t = threadIdx.x;
    if (t < 16) dec[t] = __expf(csum[bh * 16 + t]);
    float sv[16];
    #pragma unroll
    for (int c = 0; c < NCHUNK; ++c)
        sv[c] = states[((size_t)((b * 16 + c) * 64 + h)) * 256 + t];
    __syncthreads();
    float run = 0.f;
    #pragma unroll
    for (int c = 0; c < NCHUNK; ++c) {
        prevst[((size_t)((b * 16 + c) * 64 + h)) * 256 + t] = run;
        run = run * dec[c] + sv[c];
    }
}

// Fused: Y_off + D skip + SiLU(z) gating + RMSNorm -> bf16
__global__ __launch_bounds__(512, 4) void ssd_off_norm(const unsigned short* __restrict__ xcb,
                                                       const unsigned short* __restrict__ zxb,
                                                       const unsigned short* __restrict__ ypre16,
                                                       const float* __restrict__ prevst,
                                                       const float* __restrict__ csb,
                                                       const float* __restrict__ Dskip,
                                                       const float* __restrict__ normw,
                                                       unsigned short* __restrict__ yout) {
    __shared__ float Cs[16][16];
    __shared__ float csS[64][16];
    __shared__ float nw[1024];
    __shared__ float Dn[64];
    __shared__ float red[16][8];

    const int blk = blockIdx.x;
    const int bc = blk >> 4;          // b*16 + c
    const int rb = blk & 15;
    const int r0 = rb * 16;
    const int b = bc >> 4, c = bc & 15;
    const int brow0 = b * SEQ + c * CHUNK;
    const int t = threadIdx.x;
    const int ch0 = t * 2;
    const int h = ch0 >> 4;
    const int p0 = ch0 & 15;
    const int wv = t >> 6;
    const int lane = t & 63;

    if (t < 256) *(float4*)&nw[t * 4] = *(const float4*)(normw + t * 4);
    else if (t < 320) Dn[t - 256] = Dskip[t - 256];
    if (t < 64) {
        int r = t >> 2, n4 = (t & 3) * 4;
        ushort4 uu = *(const ushort4*)(xcb + (size_t)(brow0 + r0 + r) * CONV_DIM
                                       + D_INNER + D_STATE + n4);
        Cs[r][n4 + 0] = b2f(uu.x); Cs[r][n4 + 1] = b2f(uu.y);
        Cs[r][n4 + 2] = b2f(uu.z); Cs[r][n4 + 3] = b2f(uu.w);
    }
    #pragma unroll
    for (int i = t; i < 1024; i += 512) {
        int r = i & 15, hh = i >> 4;
        csS[hh][r] = csb[(size_t)(bc * 64 + hh) * 256 + r0 + r];
    }

    float ps[2][16];
    {
        const float* pbase = prevst + (size_t)(bc * 64 + h) * 256 + p0 * 16;
        #pragma unroll
        for (int n4 = 0; n4 < 16; n4 += 4) {
            *(float4*)&ps[0][n4] = *(const float4*)(pbase + n4);
            *(float4*)&ps[1][n4] = *(const float4*)(pbase + 16 + n4);
        }
    }
    __syncthreads();

    const float d = Dn[h];
    const float nw0 = nw[ch0], nw1 = nw[ch0 + 1];

    for (int r = 0; r < 16; ++r) {
        const size_t grow = (size_t)(brow0 + r0 + r);
        ushort2 yu = *(const ushort2*)(ypre16 + grow * D_INNER + ch0);
        ushort2 xu = *(const ushort2*)(xcb + grow * CONV_DIM + ch0);
        ushort2 zu = *(const ushort2*)(zxb + grow * LDZX + ch0);
        float sdo = __expf(csS[h][r]);
        float off0 = 0.f, off1 = 0.f;
        #pragma unroll
        for (int n = 0; n < 16; ++n) {
            float cn = Cs[r][n];
            off0 += cn * ps[0][n];
            off1 += cn * ps[1][n];
        }
        float g0 = (b2f(yu.x) + sdo * off0 + b2f(xu.x) * d) * siluf(b2f(zu.x));
        float g1 = (b2f(yu.y) + sdo * off1 + b2f(xu.y) * d) * siluf(b2f(zu.y));
        float s = g0 * g0 + g1 * g1;
        #pragma unroll
        for (int o = 32; o > 0; o >>= 1) s += __shfl_down(s, o, 64);
        if (lane == 0) red[r][wv] = s;
        __syncthreads();
        float tot = 0.f;
        #pragma unroll
        for (int w2 = 0; w2 < 8; ++w2) tot += red[r][w2];
        float rstd = rsqrtf(tot * (1.f / (float)D_INNER) + 1e-5f);
        ushort2 o2;
        o2.x = f2b(g0 * rstd * nw0);
        o2.y = f2b(g1 * rstd * nw1);
        *(ushort2*)(yout + grow * D_INNER + ch0) = o2;
    }
}

extern "C" void kernel_launch(void* const* d_in, const int* in_sizes, int n_in,
                              void* d_out, int out_size, void* d_ws, size_t ws_size,
                              hipStream_t stream) {
    const float* u     = (const float*)d_in[0];
    const float* Win   = (const float*)d_in[1];
    const float* cw    = (const float*)d_in[2];
    const float* cb    = (const float*)d_in[3];
    const float* dtb   = (const float*)d_in[4];
    const float* Alog  = (const float*)d_in[5];
    const float* Dsk   = (const float*)d_in[6];
    const float* normw = (const float*)d_in[7];
    const float* Wout  = (const float*)d_in[8];
    float* out = (float*)d_out;

    float* ws = (float*)d_ws;
    unsigned short* zxb = (unsigned short*)ws;             // 8192*2176 bf16 = 8,912,896 f32
    float* dtsp   = ws + 8912896;                          // 524288
    float* csb    = dtsp + 524288;                         // 524288
    float* st     = csb + 524288;                          // 524288
    float* pst    = st + 524288;                           // 524288
    float* csum   = pst + 524288;                          // 2048
    unsigned short* ypre16 = (unsigned short*)(csum + 2048);            // 8192*1024 bf16 = 4,194,304 f32
    unsigned short* xcb    = (unsigned short*)((float*)ypre16 + 4194304); // 8,650,752 bf16
    unsigned short* yn_bf  = (unsigned short*)((float*)xcb + 4325376);    // 8192*1024 bf16
    unsigned short* u_bf   = (unsigned short*)((float*)yn_bf + 2097152);  // 8192*512 bf16
    unsigned short* win_bf  = (unsigned short*)((float*)u_bf + 2097152);  // 2176*512 bf16
    unsigned short* wout_bf = (unsigned short*)((float*)win_bf + 557056); // 512*1024 bf16

    cast8<<<2048, 256, 0, stream>>>(u, u_bf, 4194304);
    castpad8<<<544, 256, 0, stream>>>(Win, win_bf, 2144 * 512, 2176 * 512);
    cast8<<<256, 256, 0, stream>>>(Wout, wout_bf, 524288);

    // in_proj: bf16 C + fused softplus(dt) side-write; grid 17x64 = 1088 (%8==0)
    gemm_mfma<<<1088, 256, 0, stream>>>(u_bf, win_bf, nullptr, zxb, dtsp, dtb,
                                        D_MODEL, D_MODEL, LDZX, 17);

    conv_silu44<<<(ROWS / 4) * (CONV_DIM / 4) / 256, 256, 0, stream>>>(zxb, cw, cb, xcb);
    ssd_chunk<<<BATCH * NCHUNK * NHEADS, 256, 0, stream>>>(xcb, dtsp, Alog, ypre16, st, csb, csum);
    ssd_rec<<<BATCH * NHEADS, 256, 0, stream>>>(st, csum, pst);
    ssd_off_norm<<<512, 512, 0, stream>>>(xcb, zxb, ypre16, pst, csb, Dsk, normw, yn_bf);

    // out_proj: fp32 C; grid 4x64 = 256 (%8==0)
    gemm_mfma<<<256, 256, 0, stream>>>(yn_bf, wout_bf, out, nullptr, nullptr, nullptr,
                                       D_INNER, D_INNER, 0, 4);
}

// Round 8
// 145.370 us; speedup vs baseline: 4.8904x; 1.0281x over previous
//
#include <hip/hip_runtime.h>
#include <hip/hip_bf16.h>
#include <math.h>

#define D_MODEL   512
#define D_INNER   1024
#define NHEADS    64
#define HEADDIM   16
#define D_STATE   16
#define CONV_DIM  1056
#define D_IN_PROJ 2144
#define CHUNK     256
#define NCHUNK    16
#define BATCH     2
#define SEQ       4096
#define ROWS      (BATCH * SEQ)   // 8192
#define LDZX      2176            // padded bf16 row stride of zx

typedef __bf16    bf16x8 __attribute__((ext_vector_type(8)));
typedef _Float16  f16x8  __attribute__((ext_vector_type(8)));
typedef float     f32x4  __attribute__((ext_vector_type(4)));
typedef float     f32x16 __attribute__((ext_vector_type(16)));
typedef unsigned short u16x8 __attribute__((ext_vector_type(8)));
typedef unsigned int   u32x4 __attribute__((ext_vector_type(4)));

__device__ __forceinline__ float softplusf(float x) {
    return (x > 20.f) ? x : log1pf(expf(x));
}
__device__ __forceinline__ float siluf(float x) {
    return x / (1.f + expf(-x));
}
__device__ __forceinline__ unsigned short f2b(float x) {
    union { __hip_bfloat16 h; unsigned short u; } cv;
    cv.h = __float2bfloat16(x);
    return cv.u;
}
__device__ __forceinline__ float b2f(unsigned short u) {
    union { float f; unsigned int i; } c;
    c.i = (unsigned int)u << 16;
    return c.f;
}
__device__ __forceinline__ void load_lds16(const unsigned short* g, unsigned short* l) {
    __builtin_amdgcn_global_load_lds(
        (const __attribute__((address_space(1))) void*)g,
        (__attribute__((address_space(3))) void*)l,
        16, 0, 0);
}

// ---- cast fp32 -> bf16 ----
__global__ __launch_bounds__(256) void cast8(const float* __restrict__ in,
                                             unsigned short* __restrict__ out, int n) {
    int i = (blockIdx.x * blockDim.x + threadIdx.x) * 8;
    if (i >= n) return;
    float4 a = *(const float4*)(in + i);
    float4 b = *(const float4*)(in + i + 4);
    u16x8 o;
    o[0] = f2b(a.x); o[1] = f2b(a.y); o[2] = f2b(a.z); o[3] = f2b(a.w);
    o[4] = f2b(b.x); o[5] = f2b(b.y); o[6] = f2b(b.z); o[7] = f2b(b.w);
    *(u16x8*)(out + i) = o;
}

__global__ __launch_bounds__(256) void castpad8(const float* __restrict__ in,
                                                unsigned short* __restrict__ out,
                                                int n, int npad) {
    int i = (blockIdx.x * blockDim.x + threadIdx.x) * 8;
    if (i >= npad) return;
    u16x8 o;
    if (i + 8 <= n) {
        float4 a = *(const float4*)(in + i);
        float4 b = *(const float4*)(in + i + 4);
        o[0] = f2b(a.x); o[1] = f2b(a.y); o[2] = f2b(a.z); o[3] = f2b(a.w);
        o[4] = f2b(b.x); o[5] = f2b(b.y); o[6] = f2b(b.z); o[7] = f2b(b.w);
    } else {
        #pragma unroll
        for (int j = 0; j < 8; ++j) o[j] = (i + j < n) ? f2b(in[i + j]) : (unsigned short)0;
    }
    *(u16x8*)(out + i) = o;
}

// ---- in_proj GEMM: zx[8192,2176(bf16)] = u[8192,512] @ Win[2176,512]^T
// 128x128 tile, double-buffered, XCD-swizzled, direct bf16 stores + fused softplus(dt).
__global__ __launch_bounds__(256) void gemm_in(const unsigned short* __restrict__ A,
                                               const unsigned short* __restrict__ B,
                                               unsigned short* __restrict__ C16,
                                               float* __restrict__ dtsp,
                                               const float* __restrict__ dtb) {
    __shared__ unsigned short smem[16384];   // A dbuf [0,8192), B dbuf [8192,16384)
    const int t    = threadIdx.x;
    const int wave = t >> 6;
    const int lane = t & 63;
    const int bid  = blockIdx.x;             // grid 1088 = 17x64
    const int swz  = (bid & 7) * 136 + (bid >> 3);
    const int by   = swz / 17;
    const int bx   = swz - by * 17;
    const int bm   = by * 128;
    const int bn   = bx * 128;
    const int wr   = wave >> 1;
    const int wc   = wave & 1;

    const int srow = wave * 16 + (lane >> 2);
    const int scol = (lane & 3) * 8;
    const unsigned short* ga0 = A + (size_t)(bm + srow) * 512 + scol;
    const unsigned short* ga1 = A + (size_t)(bm + 64 + srow) * 512 + scol;
    const unsigned short* gb0 = B + (size_t)(bn + srow) * 512 + scol;
    const unsigned short* gb1 = B + (size_t)(bn + 64 + srow) * 512 + scol;

    const int fr = lane & 15;
    const int kb = (lane >> 4) * 8;

    f32x4 acc[4][4] = {};

    load_lds16(ga0, smem + wave * 512);
    load_lds16(ga1, smem + 2048 + wave * 512);
    load_lds16(gb0, smem + 8192 + wave * 512);
    load_lds16(gb1, smem + 8192 + 2048 + wave * 512);
    __syncthreads();

    int cur = 0;
    for (int it = 0; it < 16; ++it) {
        if (it + 1 < 16) {
            const int k0 = (it + 1) * 32;
            const int nb = cur ^ 1;
            load_lds16(ga0 + k0, smem + nb * 4096 + wave * 512);
            load_lds16(ga1 + k0, smem + nb * 4096 + 2048 + wave * 512);
            load_lds16(gb0 + k0, smem + 8192 + nb * 4096 + wave * 512);
            load_lds16(gb1 + k0, smem + 8192 + nb * 4096 + 2048 + wave * 512);
        }
        const unsigned short* Ab = smem + cur * 4096;
        const unsigned short* Bb = smem + 8192 + cur * 4096;
        bf16x8 af[4], bfr[4];
        #pragma unroll
        for (int m = 0; m < 4; ++m)
            af[m] = *reinterpret_cast<const bf16x8*>(&Ab[(wr * 64 + m * 16 + fr) * 32 + kb]);
        #pragma unroll
        for (int n = 0; n < 4; ++n)
            bfr[n] = *reinterpret_cast<const bf16x8*>(&Bb[(wc * 64 + n * 16 + fr) * 32 + kb]);
        #pragma unroll
        for (int m = 0; m < 4; ++m)
            #pragma unroll
            for (int n = 0; n < 4; ++n)
                acc[m][n] = __builtin_amdgcn_mfma_f32_16x16x32_bf16(af[m], bfr[n], acc[m][n], 0, 0, 0);
        __syncthreads();
        cur ^= 1;
    }

    // fused softplus(dt) side-write: only block-column bn==2048 covers cols 2080..2143
    if (bn == 2048) {
        #pragma unroll
        for (int m = 0; m < 4; ++m) {
            #pragma unroll
            for (int n = 0; n < 4; ++n) {
                const int col = bn + wc * 64 + fr + n * 16;
                if (col >= 2080 && col < 2144) {
                    const int h = col - 2080;
                    const float bias = dtb[h];
                    #pragma unroll
                    for (int j = 0; j < 4; ++j) {
                        const int row = bm + wr * 64 + ((lane >> 4) << 2) + m * 16 + j;
                        dtsp[(size_t)row * 64 + h] = softplusf(acc[m][n][j] + bias);
                    }
                }
            }
        }
    }
    const int cr0 = bm + wr * 64 + ((lane >> 4) << 2);
    const int cc0 = bn + wc * 64 + fr;
    #pragma unroll
    for (int m = 0; m < 4; ++m)
        #pragma unroll
        for (int n = 0; n < 4; ++n)
            #pragma unroll
            for (int j = 0; j < 4; ++j)
                C16[(size_t)(cr0 + m * 16 + j) * LDZX + cc0 + n * 16] = f2b(acc[m][n][j]);
}

// ---- out_proj GEMM: out[8192,512(f32)] = yn[8192,1024] @ Wout[512,1024]^T
// 128x64 tile (4 waves 2x2, 64x32 each), 24KB LDS dbuf -> 512 blocks = 2/CU.
__global__ __launch_bounds__(256) void gemm_out(const unsigned short* __restrict__ A,
                                                const unsigned short* __restrict__ B,
                                                float* __restrict__ C) {
    __shared__ unsigned short smem[12288];   // A dbuf [0,8192), B dbuf [8192,12288)
    const int t    = threadIdx.x;
    const int wave = t >> 6;
    const int lane = t & 63;
    const int bid  = blockIdx.x;             // grid 512 = 8x64
    const int swz  = (bid & 7) * 64 + (bid >> 3);
    const int by   = swz >> 3;
    const int bx   = swz & 7;
    const int bm   = by * 128;
    const int bn   = bx * 64;
    const int wr   = wave >> 1;
    const int wc   = wave & 1;

    const int srow = wave * 16 + (lane >> 2);
    const int scol = (lane & 3) * 8;
    const unsigned short* ga0 = A + (size_t)(bm + srow) * 1024 + scol;
    const unsigned short* ga1 = A + (size_t)(bm + 64 + srow) * 1024 + scol;
    const unsigned short* gb0 = B + (size_t)(bn + srow) * 1024 + scol;

    const int fr = lane & 15;
    const int kb = (lane >> 4) * 8;

    f32x4 acc[4][2] = {};

    load_lds16(ga0, smem + wave * 512);
    load_lds16(ga1, smem + 2048 + wave * 512);
    load_lds16(gb0, smem + 8192 + wave * 512);
    __syncthreads();

    int cur = 0;
    for (int it = 0; it < 32; ++it) {
        if (it + 1 < 32) {
            const int k0 = (it + 1) * 32;
            const int nb = cur ^ 1;
            load_lds16(ga0 + k0, smem + nb * 4096 + wave * 512);
            load_lds16(ga1 + k0, smem + nb * 4096 + 2048 + wave * 512);
            load_lds16(gb0 + k0, smem + 8192 + nb * 2048 + wave * 512);
        }
        const unsigned short* Ab = smem + cur * 4096;
        const unsigned short* Bb = smem + 8192 + cur * 2048;
        bf16x8 af[4], bfr[2];
        #pragma unroll
        for (int m = 0; m < 4; ++m)
            af[m] = *reinterpret_cast<const bf16x8*>(&Ab[(wr * 64 + m * 16 + fr) * 32 + kb]);
        #pragma unroll
        for (int n = 0; n < 2; ++n)
            bfr[n] = *reinterpret_cast<const bf16x8*>(&Bb[(wc * 32 + n * 16 + fr) * 32 + kb]);
        #pragma unroll
        for (int m = 0; m < 4; ++m)
            #pragma unroll
            for (int n = 0; n < 2; ++n)
                acc[m][n] = __builtin_amdgcn_mfma_f32_16x16x32_bf16(af[m], bfr[n], acc[m][n], 0, 0, 0);
        __syncthreads();
        cur ^= 1;
    }

    const int cr0 = bm + wr * 64 + ((lane >> 4) << 2);
    const int cc0 = bn + wc * 32 + fr;
    #pragma unroll
    for (int m = 0; m < 4; ++m)
        #pragma unroll
        for (int n = 0; n < 2; ++n)
            #pragma unroll
            for (int j = 0; j < 4; ++j)
                C[(size_t)(cr0 + m * 16 + j) * 512 + cc0 + n * 16] = acc[m][n][j];
}

// depthwise causal conv(4) + bias + SiLU; 4 rows x 4 channels per thread
__global__ void conv_silu44(const unsigned short* __restrict__ zxb, const float* __restrict__ cw,
                            const float* __restrict__ cb, unsigned short* __restrict__ xcb) {
    int idx = blockIdx.x * blockDim.x + threadIdx.x;
    if (idx >= (ROWS / 4) * (CONV_DIM / 4)) return;
    const int cq  = idx % (CONV_DIM / 4);
    const int blq = idx / (CONV_DIM / 4);
    const int bl0 = blq * 4;
    const int l0  = bl0 % SEQ;
    const int c4  = cq * 4;
    const unsigned short* base = zxb + (size_t)bl0 * LDZX + D_INNER + c4;
    float4 w0 = *(const float4*)(cw + (c4 + 0) * 4);
    float4 w1 = *(const float4*)(cw + (c4 + 1) * 4);
    float4 w2 = *(const float4*)(cw + (c4 + 2) * 4);
    float4 w3 = *(const float4*)(cw + (c4 + 3) * 4);
    float4 bb = *(const float4*)(cb + c4);
    float4 in[7];
    #pragma unroll
    for (int k = 0; k < 7; ++k) {
        const int off = k - 3;
        if (l0 == 0 && k < 3) {
            in[k] = make_float4(0.f, 0.f, 0.f, 0.f);
        } else {
            ushort4 uu = *(const ushort4*)(base + (long)off * LDZX);
            in[k] = make_float4(b2f(uu.x), b2f(uu.y), b2f(uu.z), b2f(uu.w));
        }
    }
    #pragma unroll
    for (int r = 0; r < 4; ++r) {
        ushort4 o;
        o.x = f2b(siluf(bb.x + w0.x * in[r].x + w0.y * in[r + 1].x + w0.z * in[r + 2].x + w0.w * in[r + 3].x));
        o.y = f2b(siluf(bb.y + w1.x * in[r].y + w1.y * in[r + 1].y + w1.z * in[r + 2].y + w1.w * in[r + 3].y));
        o.z = f2b(siluf(bb.z + w2.x * in[r].z + w2.y * in[r + 1].z + w2.z * in[r + 2].z + w2.w * in[r + 3].z));
        o.w = f2b(siluf(bb.w + w3.x * in[r].w + w3.y * in[r + 1].w + w3.z * in[r + 2].w + w3.w * in[r + 3].w));
        *(ushort4*)(xcb + (size_t)(bl0 + r) * CONV_DIM + c4) = o;
    }
}

// per (b, chunk, head) block: 32x32-MFMA intra-chunk Y_diag + end-of-chunk state.
__global__ __launch_bounds__(256, 3) void ssd_chunk(const unsigned short* __restrict__ xcb,
                                                    const float* __restrict__ dtsp,
                                                    const float* __restrict__ A_log,
                                                    unsigned short* __restrict__ ypre16,
                                                    float* __restrict__ states,
                                                    float* __restrict__ csb,
                                                    float* __restrict__ csum) {
    __shared__ _Float16 Bb[256][16];
    __shared__ _Float16 Cb[256][16];
    __shared__ _Float16 Xt[16][264];
    __shared__ _Float16 Xdt[16][264];
    __shared__ _Float16 Bt[16][264];
    __shared__ float csL[256];
    __shared__ float wsumL[4];
    __shared__ float stpart[4][16][16];

    const int bid = blockIdx.x;
    const int h = bid & 63;
    const int c = (bid >> 6) & 15;
    const int b = bid >> 10;
    const int t = threadIdx.x;
    const int wv = t >> 6;
    const int lane = t & 63;
    const int fr = lane & 15;
    const int hi = lane >> 4;
    const int l31 = lane & 31;
    const int hi5 = lane >> 5;
    const int row = b * SEQ + c * CHUNK + t;

    float Ah  = -__expf(A_log[h]);
    float dtv = dtsp[(size_t)row * NHEADS + h];
    float val = dtv * Ah;
    #pragma unroll
    for (int off = 1; off < 64; off <<= 1) {
        float o = __shfl_up(val, off, 64);
        if (lane >= off) val += o;
    }
    if (lane == 63) wsumL[wv] = val;
    __syncthreads();
    float pre = 0.f, cl = 0.f;
    #pragma unroll
    for (int w2 = 0; w2 < 4; ++w2) {
        float s = wsumL[w2];
        if (w2 < wv) pre += s;
        cl += s;
    }
    float cst = val + pre;
    csL[t] = cst;
    csb[(size_t)bid * 256 + t] = cst;
    if (t == 0) csum[(b * 64 + h) * 16 + c] = cl;
    float dec_t = __expf(cl - cst);

    const unsigned short* xrow = xcb + (size_t)row * CONV_DIM;
    u16x8 braw0 = *(const u16x8*)(xrow + D_INNER);
    u16x8 braw1 = *(const u16x8*)(xrow + D_INNER + 8);
    u16x8 craw0 = *(const u16x8*)(xrow + D_INNER + D_STATE);
    u16x8 craw1 = *(const u16x8*)(xrow + D_INNER + D_STATE + 8);
    u16x8 xraw0 = *(const u16x8*)(xrow + h * HEADDIM);
    u16x8 xraw1 = *(const u16x8*)(xrow + h * HEADDIM + 8);
    float bv[16], cv[16], xv[16];
    #pragma unroll
    for (int n = 0; n < 8; ++n) {
        bv[n] = b2f(braw0[n]); bv[8 + n] = b2f(braw1[n]);
        cv[n] = b2f(craw0[n]); cv[8 + n] = b2f(craw1[n]);
        xv[n] = b2f(xraw0[n]); xv[8 + n] = b2f(xraw1[n]);
    }
    {
        f16x8 pk;
        #pragma unroll
        for (int n = 0; n < 8; ++n) pk[n] = (_Float16)cv[n];
        *(f16x8*)&Cb[t][0] = pk;
        #pragma unroll
        for (int n = 0; n < 8; ++n) pk[n] = (_Float16)cv[8 + n];
        *(f16x8*)&Cb[t][8] = pk;
        #pragma unroll
        for (int n = 0; n < 8; ++n) pk[n] = (_Float16)bv[n];
        *(f16x8*)&Bb[t][0] = pk;
        #pragma unroll
        for (int n = 0; n < 8; ++n) pk[n] = (_Float16)bv[8 + n];
        *(f16x8*)&Bb[t][8] = pk;
    }
    #pragma unroll
    for (int n = 0; n < 16; ++n) {
        Bt[n][t] = (_Float16)bv[n];
        float xd = xv[n] * dtv;
        Xt[n][t] = (_Float16)xd;
        Xdt[n][t] = (_Float16)(xd * dec_t);
    }
    __syncthreads();

    const int browbase = b * SEQ + c * CHUNK;
    const f32x16 z16 = {};

    #pragma unroll
    for (int halfi = 0; halfi < 2; ++halfi) {
        const int rt = (halfi == 0) ? wv : 7 - wv;
        const int t0 = rt * 32;
        const float cs_t = csL[t0 + l31];
        const f16x8 cfrag = *(const f16x8*)&Cb[t0 + l31][hi5 * 8];
        f32x16 yacc = {};
        for (int sb = 0; sb <= rt; ++sb) {
            const int s0 = sb * 32;
            f16x8 bfrag = *(const f16x8*)&Bb[s0 + l31][hi5 * 8];
            f32x16 sp = __builtin_amdgcn_mfma_f32_32x32x16_f16(bfrag, cfrag, z16, 0, 0, 0);
            const bool diag = (sb == rt);
            unsigned int D[8];
            #pragma unroll
            for (int j = 0; j < 8; ++j) {
                const int q0 = 2 * j;
                const int sr0 = (q0 & 3) + 8 * (q0 >> 2) + 4 * hi5;
                float p0 = sp[q0] * __expf(cs_t - csL[s0 + sr0]);
                float p1 = sp[q0 + 1] * __expf(cs_t - csL[s0 + sr0 + 1]);
                if (diag) {
                    p0 = (sr0 <= l31) ? p0 : 0.f;
                    p1 = (sr0 + 1 <= l31) ? p1 : 0.f;
                }
                D[j] = __builtin_bit_cast(unsigned int, __builtin_amdgcn_cvt_pkrtz(p0, p1));
            }
            unsigned int pD[8];
            #pragma unroll
            for (int j = 0; j < 8; ++j) pD[j] = (unsigned int)__shfl_xor((int)D[j], 32, 64);
            u32x4 fa;
            fa[0] = hi5 ? pD[2] : D[0];
            fa[1] = hi5 ? pD[3] : D[1];
            fa[2] = hi5 ? D[2] : pD[0];
            fa[3] = hi5 ? D[3] : pD[1];
            f16x8 pf0 = __builtin_bit_cast(f16x8, fa);
            f16x8 xf0 = *(const f16x8*)&Xt[fr][s0 + hi5 * 8];
            yacc = __builtin_amdgcn_mfma_f32_32x32x16_f16(pf0, xf0, yacc, 0, 0, 0);
            fa[0] = hi5 ? pD[6] : D[4];
            fa[1] = hi5 ? pD[7] : D[5];
            fa[2] = hi5 ? D[6] : pD[4];
            fa[3] = hi5 ? D[7] : pD[5];
            f16x8 pf1 = __builtin_bit_cast(f16x8, fa);
            f16x8 xf1 = *(const f16x8*)&Xt[fr][s0 + 16 + hi5 * 8];
            yacc = __builtin_amdgcn_mfma_f32_32x32x16_f16(pf1, xf1, yacc, 0, 0, 0);
        }
        if (l31 < 16) {
            #pragma unroll
            for (int q = 0; q < 16; ++q) {
                const int tr = t0 + (q & 3) + 8 * (q >> 2) + 4 * hi5;
                ypre16[(size_t)(browbase + tr) * D_INNER + h * HEADDIM + l31] = f2b(yacc[q]);
            }
        }
    }

    const int r0w = wv * 64;
    f32x4 stacc = {};
    #pragma unroll
    for (int kt = 0; kt < 2; ++kt) {
        f16x8 xa = *(const f16x8*)&Xdt[fr][r0w + kt * 32 + hi * 8];
        f16x8 bb2 = *(const f16x8*)&Bt[fr][r0w + kt * 32 + hi * 8];
        stacc = __builtin_amdgcn_mfma_f32_16x16x32_f16(xa, bb2, stacc, 0, 0, 0);
    }
    #pragma unroll
    for (int j = 0; j < 4; ++j)
        stpart[wv][hi * 4 + j][fr] = stacc[j];
    __syncthreads();
    {
        const int p = t >> 4, n = t & 15;
        float st = stpart[0][p][n] + stpart[1][p][n] + stpart[2][p][n] + stpart[3][p][n];
        states[(size_t)bid * 256 + t] = st;
    }
}

// inter-chunk recurrence: prefetch all chunk states, then serial combine in-register
__global__ __launch_bounds__(256) void ssd_rec(const float* __restrict__ states,
                                               const float* __restrict__ csum,
                                               float* __restrict__ prevst) {
    __shared__ float dec[16];
    const int bh = blockIdx.x;
    const int b = bh >> 6, h = bh & 63;
    const int t = threadIdx.x;
    if (t < 16) dec[t] = __expf(csum[bh * 16 + t]);
    float sv[16];
    #pragma unroll
    for (int c = 0; c < NCHUNK; ++c)
        sv[c] = states[((size_t)((b * 16 + c) * 64 + h)) * 256 + t];
    __syncthreads();
    float run = 0.f;
    #pragma unroll
    for (int c = 0; c < NCHUNK; ++c) {
        prevst[((size_t)((b * 16 + c) * 64 + h)) * 256 + t] = run;
        run = run * dec[c] + sv[c];
    }
}

// Fused: Y_off + D skip + SiLU(z) gating + RMSNorm -> bf16
__global__ __launch_bounds__(512, 4) void ssd_off_norm(const unsigned short* __restrict__ xcb,
                                                       const unsigned short* __restrict__ zxb,
                                                       const unsigned short* __restrict__ ypre16,
                                                       const float* __restrict__ prevst,
                                                       const float* __restrict__ csb,
                                                       const float* __restrict__ Dskip,
                                                       const float* __restrict__ normw,
                                                       unsigned short* __restrict__ yout) {
    __shared__ float Cs[16][16];
    __shared__ float csS[64][16];
    __shared__ float nw[1024];
    __shared__ float Dn[64];
    __shared__ float red[16][8];

    const int blk = blockIdx.x;
    const int bc = blk >> 4;          // b*16 + c
    const int rb = blk & 15;
    const int r0 = rb * 16;
    const int b = bc >> 4, c = bc & 15;
    const int brow0 = b * SEQ + c * CHUNK;
    const int t = threadIdx.x;
    const int ch0 = t * 2;
    const int h = ch0 >> 4;
    const int p0 = ch0 & 15;
    const int wv = t >> 6;
    const int lane = t & 63;

    if (t < 256) *(float4*)&nw[t * 4] = *(const float4*)(normw + t * 4);
    else if (t < 320) Dn[t - 256] = Dskip[t - 256];
    if (t < 64) {
        int r = t >> 2, n4 = (t & 3) * 4;
        ushort4 uu = *(const ushort4*)(xcb + (size_t)(brow0 + r0 + r) * CONV_DIM
                                       + D_INNER + D_STATE + n4);
        Cs[r][n4 + 0] = b2f(uu.x); Cs[r][n4 + 1] = b2f(uu.y);
        Cs[r][n4 + 2] = b2f(uu.z); Cs[r][n4 + 3] = b2f(uu.w);
    }
    #pragma unroll
    for (int i = t; i < 1024; i += 512) {
        int r = i & 15, hh = i >> 4;
        csS[hh][r] = csb[(size_t)(bc * 64 + hh) * 256 + r0 + r];
    }

    float ps[2][16];
    {
        const float* pbase = prevst + (size_t)(bc * 64 + h) * 256 + p0 * 16;
        #pragma unroll
        for (int n4 = 0; n4 < 16; n4 += 4) {
            *(float4*)&ps[0][n4] = *(const float4*)(pbase + n4);
            *(float4*)&ps[1][n4] = *(const float4*)(pbase + 16 + n4);
        }
    }
    __syncthreads();

    const float d = Dn[h];
    const float nw0 = nw[ch0], nw1 = nw[ch0 + 1];

    for (int r = 0; r < 16; ++r) {
        const size_t grow = (size_t)(brow0 + r0 + r);
        ushort2 yu = *(const ushort2*)(ypre16 + grow * D_INNER + ch0);
        ushort2 xu = *(const ushort2*)(xcb + grow * CONV_DIM + ch0);
        ushort2 zu = *(const ushort2*)(zxb + grow * LDZX + ch0);
        float sdo = __expf(csS[h][r]);
        float off0 = 0.f, off1 = 0.f;
        #pragma unroll
        for (int n = 0; n < 16; ++n) {
            float cn = Cs[r][n];
            off0 += cn * ps[0][n];
            off1 += cn * ps[1][n];
        }
        float g0 = (b2f(yu.x) + sdo * off0 + b2f(xu.x) * d) * siluf(b2f(zu.x));
        float g1 = (b2f(yu.y) + sdo * off1 + b2f(xu.y) * d) * siluf(b2f(zu.y));
        float s = g0 * g0 + g1 * g1;
        #pragma unroll
        for (int o = 32; o > 0; o >>= 1) s += __shfl_down(s, o, 64);
        if (lane == 0) red[r][wv] = s;
        __syncthreads();
        float tot = 0.f;
        #pragma unroll
        for (int w2 = 0; w2 < 8; ++w2) tot += red[r][w2];
        float rstd = rsqrtf(tot * (1.f / (float)D_INNER) + 1e-5f);
        ushort2 o2;
        o2.x = f2b(g0 * rstd * nw0);
        o2.y = f2b(g1 * rstd * nw1);
        *(ushort2*)(yout + grow * D_INNER + ch0) = o2;
    }
}

extern "C" void kernel_launch(void* const* d_in, const int* in_sizes, int n_in,
                              void* d_out, int out_size, void* d_ws, size_t ws_size,
                              hipStream_t stream) {
    const float* u     = (const float*)d_in[0];
    const float* Win   = (const float*)d_in[1];
    const float* cw    = (const float*)d_in[2];
    const float* cb    = (const float*)d_in[3];
    const float* dtb   = (const float*)d_in[4];
    const float* Alog  = (const float*)d_in[5];
    const float* Dsk   = (const float*)d_in[6];
    const float* normw = (const float*)d_in[7];
    const float* Wout  = (const float*)d_in[8];
    float* out = (float*)d_out;

    float* ws = (float*)d_ws;
    unsigned short* zxb = (unsigned short*)ws;             // 8192*2176 bf16 = 8,912,896 f32
    float* dtsp   = ws + 8912896;                          // 524288
    float* csb    = dtsp + 524288;                         // 524288
    float* st     = csb + 524288;                          // 524288
    float* pst    = st + 524288;                           // 524288
    float* csum   = pst + 524288;                          // 2048
    unsigned short* ypre16 = (unsigned short*)(csum + 2048);              // 8192*1024 bf16
    unsigned short* xcb    = (unsigned short*)((float*)ypre16 + 4194304); // 8,650,752 bf16
    unsigned short* yn_bf  = (unsigned short*)((float*)xcb + 4325376);    // 8192*1024 bf16
    unsigned short* u_bf   = (unsigned short*)((float*)yn_bf + 2097152);  // 8192*512 bf16
    unsigned short* win_bf  = (unsigned short*)((float*)u_bf + 2097152);  // 2176*512 bf16
    unsigned short* wout_bf = (unsigned short*)((float*)win_bf + 557056); // 512*1024 bf16

    cast8<<<2048, 256, 0, stream>>>(u, u_bf, 4194304);
    castpad8<<<544, 256, 0, stream>>>(Win, win_bf, 2144 * 512, 2176 * 512);
    cast8<<<256, 256, 0, stream>>>(Wout, wout_bf, 524288);

    gemm_in<<<1088, 256, 0, stream>>>(u_bf, win_bf, zxb, dtsp, dtb);

    conv_silu44<<<(ROWS / 4) * (CONV_DIM / 4) / 256, 256, 0, stream>>>(zxb, cw, cb, xcb);
    ssd_chunk<<<BATCH * NCHUNK * NHEADS, 256, 0, stream>>>(xcb, dtsp, Alog, ypre16, st, csb, csum);
    ssd_rec<<<BATCH * NHEADS, 256, 0, stream>>>(st, csum, pst);
    ssd_off_norm<<<512, 512, 0, stream>>>(xcb, zxb, ypre16, pst, csb, Dsk, normw, yn_bf);

    gemm_out<<<512, 256, 0, stream>>>(yn_bf, wout_bf, out);
}